// Round 8
// baseline (688.230 us; speedup 1.0000x reference)
//
#include <hip/hip_runtime.h>
#include <stdint.h>
#include <stddef.h>

#define S_LEN 1024
#define BATCH 8
#define EMB   1024
#define NHEAD 16
#define HDIM  64
#define FDIM  4096
#define NTOK  (S_LEN*BATCH)   // 8192

typedef unsigned short u16s;
typedef __attribute__((ext_vector_type(4))) float  f32x4;
typedef __attribute__((ext_vector_type(8))) u16s   u16x8;
typedef __attribute__((ext_vector_type(4))) u16s   u16x4;
typedef __attribute__((ext_vector_type(8))) __bf16 bf16x8;

__device__ __forceinline__ u16s f2bf(float f) {
  unsigned int x = __float_as_uint(f);
  return (u16s)((x + 0x7FFFu + ((x >> 16) & 1u)) >> 16);
}
__device__ __forceinline__ float bf2f(u16s u) {
  return __uint_as_float((unsigned int)u << 16);
}

__device__ __forceinline__ f32x4 mfma_bf16(u16x8 a, u16x8 b, f32x4 c) {
  return __builtin_amdgcn_mfma_f32_16x16x32_bf16(
      __builtin_bit_cast(bf16x8, a), __builtin_bit_cast(bf16x8, b), c, 0, 0, 0);
}

__device__ __forceinline__ void gload16(const void* g, void* l) {
  __builtin_amdgcn_global_load_lds(
      (const __attribute__((address_space(1))) unsigned int*)g,
      (__attribute__((address_space(3))) unsigned int*)l, 16, 0, 0);
}

#define VMCNT(n) asm volatile("s_waitcnt vmcnt(" #n ")" ::: "memory")

__device__ __forceinline__ void block_sync() {
  __builtin_amdgcn_sched_barrier(0);
  asm volatile("" ::: "memory");
  __builtin_amdgcn_s_barrier();
  asm volatile("" ::: "memory");
  __builtin_amdgcn_sched_barrier(0);
}

// ---------------- cast fp32 -> bf16 ----------------
__global__ __launch_bounds__(256) void cast_kernel(const float* __restrict__ in,
                                                   u16s* __restrict__ out, int n4) {
  int i = blockIdx.x * 256 + threadIdx.x;
  if (i < n4) {
    float4 v = ((const float4*)in)[i];
    u16x4 o;
    o[0] = f2bf(v.x); o[1] = f2bf(v.y); o[2] = f2bf(v.z); o[3] = f2bf(v.w);
    ((u16x4*)out)[i] = o;
  }
}

// ---------------- concat q/k/v biases into one 3072 vector ----------------
__global__ __launch_bounds__(256) void concat_bias_kernel(const float* __restrict__ a,
                                                          const float* __restrict__ b,
                                                          const float* __restrict__ c,
                                                          float* __restrict__ o) {
  int i = blockIdx.x * 256 + threadIdx.x;  // 0..3071
  o[i] = (i < 1024) ? a[i] : (i < 2048) ? b[i - 1024] : c[i - 2048];
}

// ---------------- z projections (B=8 rows) ----------------
__global__ __launch_bounds__(256) void zproj_kernel(const float* __restrict__ z,
                                                    const float* __restrict__ w,
                                                    const float* __restrict__ bias,
                                                    float* __restrict__ out) {
  const int o = blockIdx.x * 256 + threadIdx.x;   // 0..1023
  float acc[8] = {};
  const float* wr = w + (size_t)o * EMB;
  for (int e = 0; e < EMB; e += 4) {
    float4 wv = *(const float4*)(wr + e);
#pragma unroll
    for (int b = 0; b < 8; ++b) {
      float4 zv = *(const float4*)(z + b * EMB + e);
      acc[b] += zv.x * wv.x + zv.y * wv.y + zv.z * wv.z + zv.w * wv.w;
    }
  }
  float bb = bias[o];
#pragma unroll
  for (int b = 0; b < 8; ++b) out[b * EMB + o] = acc[b] + bb;
}

// ---------------- LayerNorm (bf16 in) ----------------
// MODE 0: write bf16 ; MODE 1: write f32 (final output)
template <int MODE>
__global__ __launch_bounds__(256) void ln_kernel(const u16s* __restrict__ y,
                                                 const float* __restrict__ gam,
                                                 const float* __restrict__ bet,
                                                 u16s* __restrict__ obf,
                                                 float* __restrict__ of) {
  const int row = blockIdx.x;
  const int t = threadIdx.x;
  const u16s* yr = y + (size_t)row * EMB;
  u16x4 raw = ((const u16x4*)yr)[t];
  float4 v;
  v.x = bf2f(raw[0]); v.y = bf2f(raw[1]); v.z = bf2f(raw[2]); v.w = bf2f(raw[3]);
  float s = v.x + v.y + v.z + v.w;
  float s2 = v.x * v.x + v.y * v.y + v.z * v.z + v.w * v.w;
#pragma unroll
  for (int m = 1; m < 64; m <<= 1) { s += __shfl_xor(s, m); s2 += __shfl_xor(s2, m); }
  __shared__ float red[8];
  const int wid = t >> 6, lane = t & 63;
  if (lane == 0) { red[wid] = s; red[4 + wid] = s2; }
  __syncthreads();
  s = red[0] + red[1] + red[2] + red[3];
  s2 = red[4] + red[5] + red[6] + red[7];
  float mu = s * (1.f / EMB);
  float var = s2 * (1.f / EMB) - mu * mu;
  float rs = rsqrtf(var + 1e-5f);
  float4 g = ((const float4*)gam)[t];
  float4 b = ((const float4*)bet)[t];
  float4 o;
  o.x = (v.x - mu) * rs * g.x + b.x;
  o.y = (v.y - mu) * rs * g.y + b.y;
  o.z = (v.z - mu) * rs * g.z + b.z;
  o.w = (v.w - mu) * rs * g.w + b.w;
  if constexpr (MODE == 0) {
    u16x4 p;
    p[0] = f2bf(o.x); p[1] = f2bf(o.y); p[2] = f2bf(o.z); p[3] = f2bf(o.w);
    ((u16x4*)(obf + (size_t)row * EMB))[t] = p;
  } else {
    ((float4*)(of + (size_t)row * EMB))[t] = o;
  }
}

// ---------------- pipelined GEMM: C = A(MxK) * B(NxK)^T + bias --------------
// Tile 256 x NB (NB=256 or 128), BK=32, 512 threads = 8 waves (2M x 4N).
// Per-wave output 128 x NB/4. Multi-buffer LDS ring (NBUF=4 @NB256 / 5 @NB128):
// iteration t computes tile t from buf[t%NBUF] and stages tile t+NBUF-1 into
// buf[(t-1)%NBUF], which was freed at the previous barrier -> race-free by
// construction; ONE barrier per K-tile; counted vmcnt((NBUF-2)*L) keeps 2-3
// tiles in flight (never drains to 0 in the loop). Drain edge cases removed
// by phantom re-stages (clamped tile index, L2-hot, dead buffer).
// LDS [256][32] row-major, 16B chunk slot = c ^ (r&3) ^ ((r>>2)&3): exactly
// 2 lanes/bank on ds_read_b128 (free). global_load_lds keeps LINEAR LDS dest;
// the XOR involution is applied to the GLOBAL source chunk (both-sides rule).
enum { EPI_QKV3 = 0, EPI_RELU = 1, EPI_RES = 2, EPI_GATE = 3 };

template <int NB, int EPI>
__global__ __launch_bounds__(512, 1) void gemm_pipe(const u16s* __restrict__ A,
                                                    const u16s* __restrict__ Bw,
                                                    const float* __restrict__ bias,
                                                    void* __restrict__ out,
                                                    const u16s* __restrict__ res,
                                                    const float* __restrict__ zg,
                                                    const float* __restrict__ zv,
                                                    int M, int N, int K, float scale) {
  constexpr int NBUF = (NB == 256) ? 4 : 5;
  constexpr int LA = 2;                    // A gloads/thread/tile (256x32x2B/8KB)
  constexpr int LB = (NB == 256) ? 2 : 1;  // B gloads/thread/tile
  constexpr int NR = NB / 64;              // B frags per wave (4 or 2)
  constexpr int ASZ = 256 * 32;            // elems per A buffer
  constexpr int BSZ = NB * 32;
  __shared__ u16s As[NBUF * ASZ];          // NB=256: 64KB ; NB=128: 80KB
  __shared__ u16s Bs[NBUF * BSZ];          // NB=256: 64KB ; NB=128: 40KB
  const int tid = threadIdx.x;
  const int wid = tid >> 6, lane = tid & 63;
  const int wm = wid >> 2, wn = wid & 3;
  const int l15 = lane & 15, l4 = lane >> 4;
  const int bm0 = blockIdx.x * 256, bn0 = blockIdx.y * NB;
  const int nkt = K >> 5;

  auto stage = [&](int kt, int buf) {
#pragma unroll
    for (int i = 0; i < LA; ++i) {
      const int ell = i * 512 + tid;            // chunk id 0..1023
      const int row = ell >> 2, slot = ell & 3;
      const int c = slot ^ ((row & 3) ^ ((row >> 2) & 3));
      gload16(A + (size_t)(bm0 + row) * K + kt * 32 + c * 8,
              As + (size_t)buf * ASZ + (size_t)(i * 512 + (tid & ~63)) * 8);
    }
#pragma unroll
    for (int i = 0; i < LB; ++i) {
      const int ell = i * 512 + tid;            // chunk id 0..NB*4-1
      const int row = ell >> 2, slot = ell & 3;
      const int c = slot ^ ((row & 3) ^ ((row >> 2) & 3));
      gload16(Bw + (size_t)(bn0 + row) * K + kt * 32 + c * 8,
              Bs + (size_t)buf * BSZ + (size_t)(i * 512 + (tid & ~63)) * 8);
    }
  };

  f32x4 acc[8][NR] = {};
  // prologue: stage tiles 0..NBUF-2
  for (int p = 0; p < NBUF - 1; ++p) stage(p < nkt ? p : nkt - 1, p);
  if constexpr (NB == 256) VMCNT(8); else VMCNT(9);   // tile0 landed
  block_sync();

  int buf = 0;
  for (int t = 0; t < nkt; ++t) {
    int nx = t + NBUF - 1; if (nx >= nkt) nx = nkt - 1;   // phantom at tail
    stage(nx, (buf + NBUF - 1) % NBUF);                    // freed last barrier
    const u16s* Ab = As + (size_t)buf * ASZ;
    const u16s* Bb = Bs + (size_t)buf * BSZ;
    u16x8 af[8], bfr[NR];
#pragma unroll
    for (int i = 0; i < 8; ++i) {
      const int row = wm * 128 + i * 16 + l15;
      const int slot = l4 ^ ((row & 3) ^ ((row >> 2) & 3));
      af[i] = *(const u16x8*)(Ab + row * 32 + slot * 8);
    }
#pragma unroll
    for (int j = 0; j < NR; ++j) {
      const int row = wn * (NB / 4) + j * 16 + l15;
      const int slot = l4 ^ ((row & 3) ^ ((row >> 2) & 3));
      bfr[j] = *(const u16x8*)(Bb + row * 32 + slot * 8);
    }
    __builtin_amdgcn_s_setprio(1);
#pragma unroll
    for (int i = 0; i < 8; ++i)
#pragma unroll
      for (int j = 0; j < NR; ++j)
        acc[i][j] = mfma_bf16(af[i], bfr[j], acc[i][j]);
    __builtin_amdgcn_s_setprio(0);
    if constexpr (NB == 256) VMCNT(8); else VMCNT(9);   // tile t+1 landed
    block_sync();
    buf = (buf + 1 == NBUF) ? 0 : buf + 1;
  }
  VMCNT(0);   // no outstanding LDS-DMA past kernel scope

  u16s* outb = (u16s*)out;
#pragma unroll
  for (int j = 0; j < NR; ++j) {
    const int gc = bn0 + wn * (NB / 4) + j * 16 + l15;
    const float bv = bias[gc];
#pragma unroll
    for (int i = 0; i < 8; ++i) {
      const int gr0 = bm0 + wm * 128 + i * 16 + l4 * 4;
#pragma unroll
      for (int r = 0; r < 4; ++r) {
        const int gr = gr0 + r;
        float v = acc[i][j][r] + bv;
        if constexpr (EPI == EPI_QKV3) {
          // columns 0..1023 -> Q (scaled), 1024..2047 -> K, 2048..3071 -> V^T
          const int which = gc >> 10, col = gc & 1023;
          const int srow = gr >> 3, b = gr & 7, h = col >> 6, d = col & 63;
          if (which == 0)
            outb[(size_t)(b * 16 + h) * 65536 + srow * 64 + d] = f2bf(v * scale);
          else if (which == 1)
            outb[8388608 + (size_t)(b * 16 + h) * 65536 + srow * 64 + d] = f2bf(v);
          else
            outb[16777216 + ((size_t)(b * 16 + h) * 64 + d) * 1024 + srow] = f2bf(v);
        } else if constexpr (EPI == EPI_RELU) {
          outb[(size_t)gr * N + gc] = f2bf(fmaxf(v, 0.f));
        } else if constexpr (EPI == EPI_RES) {
          outb[(size_t)gr * N + gc] = f2bf(v + bf2f(res[(size_t)gr * N + gc]));
        } else {  // EPI_GATE
          const float lin2 = v + zg[(gr & 7) * EMB + gc];
          const float gate = 1.f / (1.f + __expf(-lin2));
          outb[(size_t)gr * EMB + gc] =
              f2bf(bf2f(res[(size_t)gr * EMB + gc]) + gate * zv[(gr & 7) * EMB + gc]);
        }
      }
    }
  }
}

// ---------------- causal flash attention (LDS-staged, load-balanced) --------
__global__ __launch_bounds__(256) void attn_kernel(const u16s* __restrict__ Q,
                                                   const u16s* __restrict__ K,
                                                   const u16s* __restrict__ VT,
                                                   u16s* __restrict__ O) {
  __shared__ u16s Ks[32 * 72];
  __shared__ u16s Vs[64 * 40];
  __shared__ u16s Pl[4][16 * 40];
  const int p = blockIdx.x, bh = blockIdx.y;
  const int tid = threadIdx.x;
  const int wid = tid >> 6, lane = tid & 63;
  const int l15 = lane & 15, l4 = lane >> 4;
  const size_t hoff = (size_t)bh * (S_LEN * HDIM);
  const u16s* Qb = Q + hoff;
  const u16s* Kb = K + hoff;
  const u16s* Vb = VT + hoff;   // [64][1024]
  u16s* Pw = Pl[wid];
  const int b = bh >> 4, h = bh & 15;

  const int kr = tid >> 3, kc = (tid & 7) * 8;   // K: row 0..31, col 0..56
  const int vr = tid >> 2, vc = (tid & 3) * 8;   // V: row 0..63, col 0..24

  for (int half = 0; half < 2; ++half) {
    const int qt = half ? (15 - p) : p;
    const int qrow = qt * 64 + wid * 16 + l15;
    const u16x8 qf0 = *(const u16x8*)(Qb + qrow * 64 + l4 * 8);
    const u16x8 qf1 = *(const u16x8*)(Qb + qrow * 64 + 32 + l4 * 8);
    f32x4 oa[4] = {};
    float mrun = -1e30f, lsum = 0.f;
    const int nkt = 2 * qt + 2;

    u16x8 kreg = *(const u16x8*)(Kb + (size_t)kr * 64 + kc);
    u16x8 vreg = *(const u16x8*)(Vb + (size_t)vr * 1024 + vc);

    for (int kt = 0; kt < nkt; ++kt) {
      __syncthreads();
      *(u16x8*)(Ks + kr * 72 + kc) = kreg;
      *(u16x8*)(Vs + vr * 40 + vc) = vreg;
      __syncthreads();
      if (kt + 1 < nkt) {
        kreg = *(const u16x8*)(Kb + (size_t)((kt + 1) * 32 + kr) * 64 + kc);
        vreg = *(const u16x8*)(Vb + (size_t)vr * 1024 + (kt + 1) * 32 + vc);
      }
      const int kbase = kt * 32;
      f32x4 sc0 = {0.f, 0.f, 0.f, 0.f}, sc1 = {0.f, 0.f, 0.f, 0.f};
      {
        u16x8 kf00 = *(const u16x8*)(Ks + l15 * 72 + l4 * 8);
        u16x8 kf01 = *(const u16x8*)(Ks + l15 * 72 + 32 + l4 * 8);
        u16x8 kf10 = *(const u16x8*)(Ks + (16 + l15) * 72 + l4 * 8);
        u16x8 kf11 = *(const u16x8*)(Ks + (16 + l15) * 72 + 32 + l4 * 8);
        __builtin_amdgcn_s_setprio(1);
        sc0 = mfma_bf16(kf00, qf0, sc0);
        sc0 = mfma_bf16(kf01, qf1, sc0);
        sc1 = mfma_bf16(kf10, qf0, sc1);
        sc1 = mfma_bf16(kf11, qf1, sc1);
        __builtin_amdgcn_s_setprio(0);
      }
      u16x8 vf[4];
#pragma unroll
      for (int df = 0; df < 4; ++df)
        vf[df] = *(const u16x8*)(Vs + (df * 16 + l15) * 40 + l4 * 8);

      float sv[8];
      float pmax = -1e30f;
#pragma unroll
      for (int r = 0; r < 4; ++r) {
        const int kg0 = kbase + l4 * 4 + r;
        const int kg1 = kbase + 16 + l4 * 4 + r;
        const float s0 = (kg0 <= qrow) ? sc0[r] : -1e9f;
        const float s1 = (kg1 <= qrow) ? sc1[r] : -1e9f;
        sv[r] = s0; sv[4 + r] = s1;
        pmax = fmaxf(pmax, fmaxf(s0, s1));
      }
      pmax = fmaxf(pmax, __shfl_xor(pmax, 16));
      pmax = fmaxf(pmax, __shfl_xor(pmax, 32));
      const float mnew = fmaxf(mrun, pmax);
      const float fsc = __expf(mrun - mnew);
      float psum = 0.f;
#pragma unroll
      for (int i = 0; i < 8; ++i) { float pv = __expf(sv[i] - mnew); sv[i] = pv; psum += pv; }
      psum += __shfl_xor(psum, 16);
      psum += __shfl_xor(psum, 32);
      lsum = lsum * fsc + psum;
      mrun = mnew;
#pragma unroll
      for (int df = 0; df < 4; ++df) oa[df] *= fsc;

      u16x4 pk0, pk1;
#pragma unroll
      for (int r = 0; r < 4; ++r) { pk0[r] = f2bf(sv[r]); pk1[r] = f2bf(sv[4 + r]); }
      *(u16x4*)(Pw + l15 * 40 + l4 * 4) = pk0;
      *(u16x4*)(Pw + l15 * 40 + 16 + l4 * 4) = pk1;
      asm volatile("s_waitcnt lgkmcnt(0)" ::: "memory");
      const u16x8 pf = *(const u16x8*)(Pw + l15 * 40 + l4 * 8);
      __builtin_amdgcn_s_setprio(1);
#pragma unroll
      for (int df = 0; df < 4; ++df)
        oa[df] = mfma_bf16(vf[df], pf, oa[df]);
      __builtin_amdgcn_s_setprio(0);
    }
    const float inv = 1.f / lsum;
    u16s* orow = O + ((size_t)qrow * 8 + b) * EMB + h * 64;
#pragma unroll
    for (int df = 0; df < 4; ++df)
#pragma unroll
      for (int r = 0; r < 4; ++r)
        orow[df * 16 + l4 * 4 + r] = f2bf(oa[df][r] * inv);
  }
}

// ---------------- driver ----------------
extern "C" void kernel_launch(void* const* d_in, const int* in_sizes, int n_in,
                              void* d_out, int out_size, void* d_ws, size_t ws_size,
                              hipStream_t stream) {
  const float* x = (const float*)d_in[0];
  const float* z = (const float*)d_in[1];
  const float* wq = (const float*)d_in[2];  const float* bq = (const float*)d_in[3];
  const float* wk = (const float*)d_in[4];  const float* bk = (const float*)d_in[5];
  const float* wv = (const float*)d_in[6];  const float* bv = (const float*)d_in[7];
  const float* wo = (const float*)d_in[8];  const float* bo = (const float*)d_in[9];
  const float* ln1g = (const float*)d_in[10]; const float* ln1b = (const float*)d_in[11];
  const float* pghw = (const float*)d_in[12]; const float* pghb = (const float*)d_in[13];
  const float* pgzw = (const float*)d_in[14]; const float* pgzb = (const float*)d_in[15];
  const float* pvw  = (const float*)d_in[16]; const float* pvb  = (const float*)d_in[17];
  const float* ln2g = (const float*)d_in[18]; const float* ln2b = (const float*)d_in[19];
  const float* fc1w = (const float*)d_in[20]; const float* fc1b = (const float*)d_in[21];
  const float* fc2w = (const float*)d_in[22]; const float* fc2b = (const float*)d_in[23];
  const float* ln3g = (const float*)d_in[24]; const float* ln3b = (const float*)d_in[25];

  char* ws = (char*)d_ws;
  size_t off = 0;
  auto alloc = [&](size_t bytes) -> char* {
    char* p = ws + off;
    off += (bytes + 255) & ~(size_t)255;
    return p;
  };

  u16s* bw_qkv = (u16s*)alloc(2u * 3145728);  // wq|wk|wv concat (3072x1024)
  u16s* bw_o = (u16s*)alloc(2u * 1048576);
  u16s* bw_g = (u16s*)alloc(2u * 1048576);
  u16s* bw_f1 = (u16s*)alloc(2u * 4194304);
  u16s* bw_f2 = (u16s*)alloc(2u * 4194304);
  u16s* xb = (u16s*)alloc(2u * 8388608);
  // qh, kh, vT, attnb are four contiguous 16MB buffers (the QKV3 epilogue
  // relies on qh+8388608 == kh, qh+16777216 == vT); hbuf (8192x4096 bf16 =
  // 64MB) aliases all four. vT is V pre-transposed per head: vT[bh][64][1024].
  u16s* qh = (u16s*)alloc(2u * 8388608);
  u16s* kh = (u16s*)alloc(2u * 8388608);
  u16s* vT = (u16s*)alloc(2u * 8388608);
  u16s* attnb = (u16s*)alloc(2u * 8388608);
  u16s* hbuf = qh;
  u16s* ybufb = (u16s*)alloc(2u * 8388608);   // bf16 pre-LN buffer
  u16s* x1b = (u16s*)alloc(2u * 8388608);     // LN1 output (bf16)
  u16s* x2b = (u16s*)alloc(2u * 8388608);     // LN2 output (bf16)
  float* zgb = (float*)alloc(4u * 8192);
  float* zvb = (float*)alloc(4u * 8192);
  float* bqkv = (float*)alloc(4u * 3072);
  (void)off; (void)ws_size; (void)in_sizes; (void)n_in; (void)out_size;
  (void)kh; (void)vT;

  auto cast = [&](const float* in, u16s* out, int n) {
    cast_kernel<<<n / 1024, 256, 0, stream>>>(in, out, n / 4);
  };
  cast(x, xb, 8388608);
  cast(wq, bw_qkv, 1048576);
  cast(wk, bw_qkv + 1048576, 1048576);
  cast(wv, bw_qkv + 2097152, 1048576);
  cast(wo, bw_o, 1048576);
  cast(pghw, bw_g, 1048576);
  cast(fc1w, bw_f1, 4194304);
  cast(fc2w, bw_f2, 4194304);
  concat_bias_kernel<<<12, 256, 0, stream>>>(bq, bk, bv, bqkv);

  // fused QKV projection (N=3072) with head-scatter epilogue
  gemm_pipe<256, EPI_QKV3><<<dim3(32, 12), 512, 0, stream>>>(
      xb, bw_qkv, bqkv, qh, nullptr, nullptr, nullptr, NTOK, 3072, EMB, 0.125f);

  attn_kernel<<<dim3(8, 128), 256, 0, stream>>>(qh, kh, vT, attnb);

  // out-proj + residual(xb) -> ybufb (bf16), then LN1 -> x1b
  gemm_pipe<128, EPI_RES><<<dim3(32, 8), 512, 0, stream>>>(
      attnb, bw_o, bo, ybufb, xb, nullptr, nullptr, NTOK, EMB, EMB, 1.f);
  ln_kernel<0><<<NTOK, 256, 0, stream>>>(ybufb, ln1g, ln1b, x1b, nullptr);

  // gated fusion (residual x1b) -> ybufb, then LN2 -> x2b
  zproj_kernel<<<4, 256, 0, stream>>>(z, pgzw, pgzb, zgb);
  zproj_kernel<<<4, 256, 0, stream>>>(z, pvw, pvb, zvb);
  gemm_pipe<128, EPI_GATE><<<dim3(32, 8), 512, 0, stream>>>(
      x1b, bw_g, pghb, ybufb, x1b, zgb, zvb, NTOK, EMB, EMB, 1.f);
  ln_kernel<0><<<NTOK, 256, 0, stream>>>(ybufb, ln2g, ln2b, x2b, nullptr);

  // FFN (residual x2b) -> ybufb, then LN3 -> d_out (f32)
  gemm_pipe<256, EPI_RELU><<<dim3(32, 16), 512, 0, stream>>>(
      x2b, bw_f1, fc1b, hbuf, nullptr, nullptr, nullptr, NTOK, FDIM, EMB, 1.f);
  gemm_pipe<128, EPI_RES><<<dim3(32, 8), 512, 0, stream>>>(
      hbuf, bw_f2, fc2b, ybufb, x2b, nullptr, nullptr, NTOK, EMB, FDIM, 1.f);
  ln_kernel<1><<<NTOK, 256, 0, stream>>>(ybufb, ln3g, ln3b, nullptr, (float*)d_out);
}

// Round 9
// 591.569 us; speedup vs baseline: 1.1634x; 1.1634x over previous
//
#include <hip/hip_runtime.h>
#include <stdint.h>
#include <stddef.h>

#define S_LEN 1024
#define BATCH 8
#define EMB   1024
#define NHEAD 16
#define HDIM  64
#define FDIM  4096
#define NTOK  (S_LEN*BATCH)   // 8192

typedef unsigned short u16s;
typedef __attribute__((ext_vector_type(4))) float  f32x4;
typedef __attribute__((ext_vector_type(8))) u16s   u16x8;
typedef __attribute__((ext_vector_type(4))) u16s   u16x4;
typedef __attribute__((ext_vector_type(8))) __bf16 bf16x8;

__device__ __forceinline__ u16s f2bf(float f) {
  unsigned int x = __float_as_uint(f);
  return (u16s)((x + 0x7FFFu + ((x >> 16) & 1u)) >> 16);
}
__device__ __forceinline__ float bf2f(u16s u) {
  return __uint_as_float((unsigned int)u << 16);
}

__device__ __forceinline__ f32x4 mfma_bf16(u16x8 a, u16x8 b, f32x4 c) {
  return __builtin_amdgcn_mfma_f32_16x16x32_bf16(
      __builtin_bit_cast(bf16x8, a), __builtin_bit_cast(bf16x8, b), c, 0, 0, 0);
}

__device__ __forceinline__ void gload16(const void* g, void* l) {
  __builtin_amdgcn_global_load_lds(
      (const __attribute__((address_space(1))) unsigned int*)g,
      (__attribute__((address_space(3))) unsigned int*)l, 16, 0, 0);
}

// ---------------- cast fp32 -> bf16 ----------------
__global__ __launch_bounds__(256) void cast_kernel(const float* __restrict__ in,
                                                   u16s* __restrict__ out, int n4) {
  int i = blockIdx.x * 256 + threadIdx.x;
  if (i < n4) {
    float4 v = ((const float4*)in)[i];
    u16x4 o;
    o[0] = f2bf(v.x); o[1] = f2bf(v.y); o[2] = f2bf(v.z); o[3] = f2bf(v.w);
    ((u16x4*)out)[i] = o;
  }
}

// ---------------- concat q/k/v biases into one 3072 vector ----------------
__global__ __launch_bounds__(256) void concat_bias_kernel(const float* __restrict__ a,
                                                          const float* __restrict__ b,
                                                          const float* __restrict__ c,
                                                          float* __restrict__ o) {
  int i = blockIdx.x * 256 + threadIdx.x;  // 0..3071
  o[i] = (i < 1024) ? a[i] : (i < 2048) ? b[i - 1024] : c[i - 2048];
}

// ---------------- z projections (B=8 rows) ----------------
__global__ __launch_bounds__(256) void zproj_kernel(const float* __restrict__ z,
                                                    const float* __restrict__ w,
                                                    const float* __restrict__ bias,
                                                    float* __restrict__ out) {
  const int o = blockIdx.x * 256 + threadIdx.x;   // 0..1023
  float acc[8] = {};
  const float* wr = w + (size_t)o * EMB;
  for (int e = 0; e < EMB; e += 4) {
    float4 wv = *(const float4*)(wr + e);
#pragma unroll
    for (int b = 0; b < 8; ++b) {
      float4 zv = *(const float4*)(z + b * EMB + e);
      acc[b] += zv.x * wv.x + zv.y * wv.y + zv.z * wv.z + zv.w * wv.w;
    }
  }
  float bb = bias[o];
#pragma unroll
  for (int b = 0; b < 8; ++b) out[b * EMB + o] = acc[b] + bb;
}

// ---------------- LayerNorm (bf16 in) ----------------
// MODE 0: write bf16 ; MODE 1: write f32 (final output)
template <int MODE>
__global__ __launch_bounds__(256) void ln_kernel(const u16s* __restrict__ y,
                                                 const float* __restrict__ gam,
                                                 const float* __restrict__ bet,
                                                 u16s* __restrict__ obf,
                                                 float* __restrict__ of) {
  const int row = blockIdx.x;
  const int t = threadIdx.x;
  const u16s* yr = y + (size_t)row * EMB;
  u16x4 raw = ((const u16x4*)yr)[t];
  float4 v;
  v.x = bf2f(raw[0]); v.y = bf2f(raw[1]); v.z = bf2f(raw[2]); v.w = bf2f(raw[3]);
  float s = v.x + v.y + v.z + v.w;
  float s2 = v.x * v.x + v.y * v.y + v.z * v.z + v.w * v.w;
#pragma unroll
  for (int m = 1; m < 64; m <<= 1) { s += __shfl_xor(s, m); s2 += __shfl_xor(s2, m); }
  __shared__ float red[8];
  const int wid = t >> 6, lane = t & 63;
  if (lane == 0) { red[wid] = s; red[4 + wid] = s2; }
  __syncthreads();
  s = red[0] + red[1] + red[2] + red[3];
  s2 = red[4] + red[5] + red[6] + red[7];
  float mu = s * (1.f / EMB);
  float var = s2 * (1.f / EMB) - mu * mu;
  float rs = rsqrtf(var + 1e-5f);
  float4 g = ((const float4*)gam)[t];
  float4 b = ((const float4*)bet)[t];
  float4 o;
  o.x = (v.x - mu) * rs * g.x + b.x;
  o.y = (v.y - mu) * rs * g.y + b.y;
  o.z = (v.z - mu) * rs * g.z + b.z;
  o.w = (v.w - mu) * rs * g.w + b.w;
  if constexpr (MODE == 0) {
    u16x4 p;
    p[0] = f2bf(o.x); p[1] = f2bf(o.y); p[2] = f2bf(o.z); p[3] = f2bf(o.w);
    ((u16x4*)(obf + (size_t)row * EMB))[t] = p;
  } else {
    ((float4*)(of + (size_t)row * EMB))[t] = o;
  }
}

// ---------------- GEMM: C = A(MxK) * B(NxK)^T + bias, fused epilogues --------
// R7 structure (best measured): 128x128 tile, BK=64, 4 waves (2x2), 32KB LDS,
// 4 blocks/CU, 2 barriers per K-tile; XOR chunk swizzle (conflicts==0).
// NEW vs R7: (1) mfma operand order swapped -> lane owns 1 M-row x 4
// consecutive N-cols -> epilogue is one u16x4 store (+u16x4/float4 res/bias
// loads) instead of 4 stride-N scalar stores; (2) grids are bn-FAST
// (blockIdx.x = N-tile) so consecutive blocks reuse the A row-panel and the
// small weight matrix stays L2-resident (R7 was bm-fast: A re-fetched per
// bn-stripe -> fc1 FETCH 43MB vs 24MB ideal).
enum { EPI_QKV3 = 0, EPI_RELU = 1, EPI_RES = 2, EPI_GATE = 3 };

template <int EPI>
__global__ __launch_bounds__(256, 4) void gemm_nt(const u16s* __restrict__ A,
                                                  const u16s* __restrict__ Bw,
                                                  const float* __restrict__ bias,
                                                  void* __restrict__ out,
                                                  const u16s* __restrict__ res,
                                                  const float* __restrict__ zg,
                                                  const float* __restrict__ zv,
                                                  int M, int N, int K, float scale) {
  __shared__ u16s As[128 * 64];
  __shared__ u16s Bs[128 * 64];
  const int tid = threadIdx.x;
  const int wid = tid >> 6, lane = tid & 63;
  const int wm = wid >> 1, wn = wid & 1;
  const int l15 = lane & 15, l4 = lane >> 4;
  const int bn0 = blockIdx.x * 128, bm0 = blockIdx.y * 128;   // bn FAST axis

  const int wbase = tid & ~63;
  // per-thread staging source (linear LDS chunk ell = ii*256 + tid)
  int srowA[4], scolA[4];
#pragma unroll
  for (int ii = 0; ii < 4; ++ii) {
    const int ell = ii * 256 + tid;
    const int row = ell >> 3;
    srowA[ii] = row;
    scolA[ii] = ((ell & 7) ^ (row & 7)) * 8;
  }

  f32x4 acc[4][4] = {};
  const int nkt = K >> 6;
  for (int kt = 0; kt < nkt; ++kt) {
#pragma unroll
    for (int ii = 0; ii < 4; ++ii) {
      gload16(A + (size_t)(bm0 + srowA[ii]) * K + kt * 64 + scolA[ii],
              As + (size_t)(ii * 256 + wbase) * 8);
      gload16(Bw + (size_t)(bn0 + srowA[ii]) * K + kt * 64 + scolA[ii],
              Bs + (size_t)(ii * 256 + wbase) * 8);
    }
    __syncthreads();
#pragma unroll
    for (int kk = 0; kk < 2; ++kk) {
      const int cs = kk * 4 + l4;
      u16x8 af[4], bfr[4];
#pragma unroll
      for (int i = 0; i < 4; ++i) {
        const int row = wm * 64 + i * 16 + l15;
        af[i] = *(const u16x8*)(As + row * 64 + (cs ^ (l15 & 7)) * 8);
      }
#pragma unroll
      for (int j = 0; j < 4; ++j) {
        const int row = wn * 64 + j * 16 + l15;
        bfr[j] = *(const u16x8*)(Bs + row * 64 + (cs ^ (l15 & 7)) * 8);
      }
      __builtin_amdgcn_s_setprio(1);
#pragma unroll
      for (int i = 0; i < 4; ++i)
#pragma unroll
        for (int j = 0; j < 4; ++j)
          acc[i][j] = mfma_bf16(bfr[j], af[i], acc[i][j]);   // swapped: lane = 1 row x 4 cols
      __builtin_amdgcn_s_setprio(0);
    }
    __syncthreads();
  }

  // epilogue: lane owns M-row gr = bm0+wm*64+i*16+l15, N-cols gc0..gc0+3
  u16s* outb = (u16s*)out;
#pragma unroll
  for (int i = 0; i < 4; ++i) {
    const int gr = bm0 + wm * 64 + i * 16 + l15;
#pragma unroll
    for (int j = 0; j < 4; ++j) {
      const int gc0 = bn0 + wn * 64 + j * 16 + l4 * 4;
      const float4 bv = *(const float4*)(bias + gc0);
      float v0 = acc[i][j][0] + bv.x, v1 = acc[i][j][1] + bv.y;
      float v2 = acc[i][j][2] + bv.z, v3 = acc[i][j][3] + bv.w;
      if constexpr (EPI == EPI_QKV3) {
        const int which = gc0 >> 10, col0 = gc0 & 1023;
        const int srow = gr >> 3, b = gr & 7, h = col0 >> 6, d0 = col0 & 63;
        if (which == 0) {
          u16x4 p; p[0] = f2bf(v0 * scale); p[1] = f2bf(v1 * scale);
          p[2] = f2bf(v2 * scale); p[3] = f2bf(v3 * scale);
          *(u16x4*)(outb + (size_t)(b * 16 + h) * 65536 + srow * 64 + d0) = p;
        } else if (which == 1) {
          u16x4 p; p[0] = f2bf(v0); p[1] = f2bf(v1); p[2] = f2bf(v2); p[3] = f2bf(v3);
          *(u16x4*)(outb + 8388608 + (size_t)(b * 16 + h) * 65536 + srow * 64 + d0) = p;
        } else {
          outb[16777216 + ((size_t)(b * 16 + h) * 64 + d0 + 0) * 1024 + srow] = f2bf(v0);
          outb[16777216 + ((size_t)(b * 16 + h) * 64 + d0 + 1) * 1024 + srow] = f2bf(v1);
          outb[16777216 + ((size_t)(b * 16 + h) * 64 + d0 + 2) * 1024 + srow] = f2bf(v2);
          outb[16777216 + ((size_t)(b * 16 + h) * 64 + d0 + 3) * 1024 + srow] = f2bf(v3);
        }
      } else if constexpr (EPI == EPI_RELU) {
        u16x4 p; p[0] = f2bf(fmaxf(v0, 0.f)); p[1] = f2bf(fmaxf(v1, 0.f));
        p[2] = f2bf(fmaxf(v2, 0.f)); p[3] = f2bf(fmaxf(v3, 0.f));
        *(u16x4*)(outb + (size_t)gr * N + gc0) = p;
      } else if constexpr (EPI == EPI_RES) {
        const u16x4 rr = *(const u16x4*)(res + (size_t)gr * N + gc0);
        u16x4 p; p[0] = f2bf(v0 + bf2f(rr[0])); p[1] = f2bf(v1 + bf2f(rr[1]));
        p[2] = f2bf(v2 + bf2f(rr[2])); p[3] = f2bf(v3 + bf2f(rr[3]));
        *(u16x4*)(outb + (size_t)gr * N + gc0) = p;
      } else {  // EPI_GATE
        const float4 zg4 = *(const float4*)(zg + (gr & 7) * EMB + gc0);
        const float4 zv4 = *(const float4*)(zv + (gr & 7) * EMB + gc0);
        const u16x4 rr = *(const u16x4*)(res + (size_t)gr * EMB + gc0);
        u16x4 p;
        p[0] = f2bf(bf2f(rr[0]) + zv4.x / (1.f + __expf(-(v0 + zg4.x))));
        p[1] = f2bf(bf2f(rr[1]) + zv4.y / (1.f + __expf(-(v1 + zg4.y))));
        p[2] = f2bf(bf2f(rr[2]) + zv4.z / (1.f + __expf(-(v2 + zg4.z))));
        p[3] = f2bf(bf2f(rr[3]) + zv4.w / (1.f + __expf(-(v3 + zg4.w))));
        *(u16x4*)(outb + (size_t)gr * EMB + gc0) = p;
      }
    }
  }
}

// ---------------- causal flash attention (LDS-staged, load-balanced) --------
__global__ __launch_bounds__(256) void attn_kernel(const u16s* __restrict__ Q,
                                                   const u16s* __restrict__ K,
                                                   const u16s* __restrict__ VT,
                                                   u16s* __restrict__ O) {
  __shared__ u16s Ks[32 * 72];
  __shared__ u16s Vs[64 * 40];
  __shared__ u16s Pl[4][16 * 40];
  const int p = blockIdx.x, bh = blockIdx.y;
  const int tid = threadIdx.x;
  const int wid = tid >> 6, lane = tid & 63;
  const int l15 = lane & 15, l4 = lane >> 4;
  const size_t hoff = (size_t)bh * (S_LEN * HDIM);
  const u16s* Qb = Q + hoff;
  const u16s* Kb = K + hoff;
  const u16s* Vb = VT + hoff;   // [64][1024]
  u16s* Pw = Pl[wid];
  const int b = bh >> 4, h = bh & 15;

  const int kr = tid >> 3, kc = (tid & 7) * 8;   // K: row 0..31, col 0..56
  const int vr = tid >> 2, vc = (tid & 3) * 8;   // V: row 0..63, col 0..24

  for (int half = 0; half < 2; ++half) {
    const int qt = half ? (15 - p) : p;
    const int qrow = qt * 64 + wid * 16 + l15;
    const u16x8 qf0 = *(const u16x8*)(Qb + qrow * 64 + l4 * 8);
    const u16x8 qf1 = *(const u16x8*)(Qb + qrow * 64 + 32 + l4 * 8);
    f32x4 oa[4] = {};
    float mrun = -1e30f, lsum = 0.f;
    const int nkt = 2 * qt + 2;

    u16x8 kreg = *(const u16x8*)(Kb + (size_t)kr * 64 + kc);
    u16x8 vreg = *(const u16x8*)(Vb + (size_t)vr * 1024 + vc);

    for (int kt = 0; kt < nkt; ++kt) {
      __syncthreads();
      *(u16x8*)(Ks + kr * 72 + kc) = kreg;
      *(u16x8*)(Vs + vr * 40 + vc) = vreg;
      __syncthreads();
      if (kt + 1 < nkt) {
        kreg = *(const u16x8*)(Kb + (size_t)((kt + 1) * 32 + kr) * 64 + kc);
        vreg = *(const u16x8*)(Vb + (size_t)vr * 1024 + (kt + 1) * 32 + vc);
      }
      const int kbase = kt * 32;
      f32x4 sc0 = {0.f, 0.f, 0.f, 0.f}, sc1 = {0.f, 0.f, 0.f, 0.f};
      {
        u16x8 kf00 = *(const u16x8*)(Ks + l15 * 72 + l4 * 8);
        u16x8 kf01 = *(const u16x8*)(Ks + l15 * 72 + 32 + l4 * 8);
        u16x8 kf10 = *(const u16x8*)(Ks + (16 + l15) * 72 + l4 * 8);
        u16x8 kf11 = *(const u16x8*)(Ks + (16 + l15) * 72 + 32 + l4 * 8);
        __builtin_amdgcn_s_setprio(1);
        sc0 = mfma_bf16(kf00, qf0, sc0);
        sc0 = mfma_bf16(kf01, qf1, sc0);
        sc1 = mfma_bf16(kf10, qf0, sc1);
        sc1 = mfma_bf16(kf11, qf1, sc1);
        __builtin_amdgcn_s_setprio(0);
      }
      u16x8 vf[4];
#pragma unroll
      for (int df = 0; df < 4; ++df)
        vf[df] = *(const u16x8*)(Vs + (df * 16 + l15) * 40 + l4 * 8);

      float sv[8];
      float pmax = -1e30f;
#pragma unroll
      for (int r = 0; r < 4; ++r) {
        const int kg0 = kbase + l4 * 4 + r;
        const int kg1 = kbase + 16 + l4 * 4 + r;
        const float s0 = (kg0 <= qrow) ? sc0[r] : -1e9f;
        const float s1 = (kg1 <= qrow) ? sc1[r] : -1e9f;
        sv[r] = s0; sv[4 + r] = s1;
        pmax = fmaxf(pmax, fmaxf(s0, s1));
      }
      pmax = fmaxf(pmax, __shfl_xor(pmax, 16));
      pmax = fmaxf(pmax, __shfl_xor(pmax, 32));
      const float mnew = fmaxf(mrun, pmax);
      const float fsc = __expf(mrun - mnew);
      float psum = 0.f;
#pragma unroll
      for (int i = 0; i < 8; ++i) { float pv = __expf(sv[i] - mnew); sv[i] = pv; psum += pv; }
      psum += __shfl_xor(psum, 16);
      psum += __shfl_xor(psum, 32);
      lsum = lsum * fsc + psum;
      mrun = mnew;
#pragma unroll
      for (int df = 0; df < 4; ++df) oa[df] *= fsc;

      u16x4 pk0, pk1;
#pragma unroll
      for (int r = 0; r < 4; ++r) { pk0[r] = f2bf(sv[r]); pk1[r] = f2bf(sv[4 + r]); }
      *(u16x4*)(Pw + l15 * 40 + l4 * 4) = pk0;
      *(u16x4*)(Pw + l15 * 40 + 16 + l4 * 4) = pk1;
      asm volatile("s_waitcnt lgkmcnt(0)" ::: "memory");
      const u16x8 pf = *(const u16x8*)(Pw + l15 * 40 + l4 * 8);
      __builtin_amdgcn_s_setprio(1);
#pragma unroll
      for (int df = 0; df < 4; ++df)
        oa[df] = mfma_bf16(vf[df], pf, oa[df]);
      __builtin_amdgcn_s_setprio(0);
    }
    const float inv = 1.f / lsum;
    u16s* orow = O + ((size_t)qrow * 8 + b) * EMB + h * 64;
#pragma unroll
    for (int df = 0; df < 4; ++df)
#pragma unroll
      for (int r = 0; r < 4; ++r)
        orow[df * 16 + l4 * 4 + r] = f2bf(oa[df][r] * inv);
  }
}

// ---------------- driver ----------------
extern "C" void kernel_launch(void* const* d_in, const int* in_sizes, int n_in,
                              void* d_out, int out_size, void* d_ws, size_t ws_size,
                              hipStream_t stream) {
  const float* x = (const float*)d_in[0];
  const float* z = (const float*)d_in[1];
  const float* wq = (const float*)d_in[2];  const float* bq = (const float*)d_in[3];
  const float* wk = (const float*)d_in[4];  const float* bk = (const float*)d_in[5];
  const float* wv = (const float*)d_in[6];  const float* bv = (const float*)d_in[7];
  const float* wo = (const float*)d_in[8];  const float* bo = (const float*)d_in[9];
  const float* ln1g = (const float*)d_in[10]; const float* ln1b = (const float*)d_in[11];
  const float* pghw = (const float*)d_in[12]; const float* pghb = (const float*)d_in[13];
  const float* pgzw = (const float*)d_in[14]; const float* pgzb = (const float*)d_in[15];
  const float* pvw  = (const float*)d_in[16]; const float* pvb  = (const float*)d_in[17];
  const float* ln2g = (const float*)d_in[18]; const float* ln2b = (const float*)d_in[19];
  const float* fc1w = (const float*)d_in[20]; const float* fc1b = (const float*)d_in[21];
  const float* fc2w = (const float*)d_in[22]; const float* fc2b = (const float*)d_in[23];
  const float* ln3g = (const float*)d_in[24]; const float* ln3b = (const float*)d_in[25];

  char* ws = (char*)d_ws;
  size_t off = 0;
  auto alloc = [&](size_t bytes) -> char* {
    char* p = ws + off;
    off += (bytes + 255) & ~(size_t)255;
    return p;
  };

  u16s* bw_qkv = (u16s*)alloc(2u * 3145728);  // wq|wk|wv concat (3072x1024)
  u16s* bw_o = (u16s*)alloc(2u * 1048576);
  u16s* bw_g = (u16s*)alloc(2u * 1048576);
  u16s* bw_f1 = (u16s*)alloc(2u * 4194304);
  u16s* bw_f2 = (u16s*)alloc(2u * 4194304);
  u16s* xb = (u16s*)alloc(2u * 8388608);
  // qh, kh, vT, attnb are four contiguous 16MB buffers (the QKV3 epilogue
  // relies on qh+8388608 == kh, qh+16777216 == vT); hbuf (8192x4096 bf16 =
  // 64MB) aliases all four. vT is V pre-transposed per head: vT[bh][64][1024].
  u16s* qh = (u16s*)alloc(2u * 8388608);
  u16s* kh = (u16s*)alloc(2u * 8388608);
  u16s* vT = (u16s*)alloc(2u * 8388608);
  u16s* attnb = (u16s*)alloc(2u * 8388608);
  u16s* hbuf = qh;
  u16s* ybufb = (u16s*)alloc(2u * 8388608);   // bf16 pre-LN buffer
  u16s* x1b = (u16s*)alloc(2u * 8388608);     // LN1 output (bf16)
  u16s* x2b = (u16s*)alloc(2u * 8388608);     // LN2 output (bf16)
  float* zgb = (float*)alloc(4u * 8192);
  float* zvb = (float*)alloc(4u * 8192);
  float* bqkv = (float*)alloc(4u * 3072);
  (void)off; (void)ws_size; (void)in_sizes; (void)n_in; (void)out_size;
  (void)kh; (void)vT;

  auto cast = [&](const float* in, u16s* out, int n) {
    cast_kernel<<<n / 1024, 256, 0, stream>>>(in, out, n / 4);
  };
  cast(x, xb, 8388608);
  cast(wq, bw_qkv, 1048576);
  cast(wk, bw_qkv + 1048576, 1048576);
  cast(wv, bw_qkv + 2097152, 1048576);
  cast(wo, bw_o, 1048576);
  cast(pghw, bw_g, 1048576);
  cast(fc1w, bw_f1, 4194304);
  cast(fc2w, bw_f2, 4194304);
  concat_bias_kernel<<<12, 256, 0, stream>>>(bq, bk, bv, bqkv);

  // fused QKV projection (N=3072) with head-scatter epilogue; grids are
  // (N-tiles, M-tiles): bn is the fast axis.
  gemm_nt<EPI_QKV3><<<dim3(24, 64), 256, 0, stream>>>(
      xb, bw_qkv, bqkv, qh, nullptr, nullptr, nullptr, NTOK, 3072, EMB, 0.125f);

  attn_kernel<<<dim3(8, 128), 256, 0, stream>>>(qh, kh, vT, attnb);

  // out-proj + residual(xb) -> ybufb (bf16), then LN1 -> x1b
  gemm_nt<EPI_RES><<<dim3(8, 64), 256, 0, stream>>>(
      attnb, bw_o, bo, ybufb, xb, nullptr, nullptr, NTOK, EMB, EMB, 1.f);
  ln_kernel<0><<<NTOK, 256, 0, stream>>>(ybufb, ln1g, ln1b, x1b, nullptr);

  // gated fusion (residual x1b) -> ybufb, then LN2 -> x2b
  zproj_kernel<<<4, 256, 0, stream>>>(z, pgzw, pgzb, zgb);
  zproj_kernel<<<4, 256, 0, stream>>>(z, pvw, pvb, zvb);
  gemm_nt<EPI_GATE><<<dim3(8, 64), 256, 0, stream>>>(
      x1b, bw_g, pghb, ybufb, x1b, zgb, zvb, NTOK, EMB, EMB, 1.f);
  ln_kernel<0><<<NTOK, 256, 0, stream>>>(ybufb, ln2g, ln2b, x2b, nullptr);

  // FFN (residual x2b) -> ybufb, then LN3 -> d_out (f32)
  gemm_nt<EPI_RELU><<<dim3(32, 64), 256, 0, stream>>>(
      x2b, bw_f1, fc1b, hbuf, nullptr, nullptr, nullptr, NTOK, FDIM, EMB, 1.f);
  gemm_nt<EPI_RES><<<dim3(8, 64), 256, 0, stream>>>(
      hbuf, bw_f2, fc2b, ybufb, x2b, nullptr, nullptr, NTOK, EMB, FDIM, 1.f);
  ln_kernel<1><<<NTOK, 256, 0, stream>>>(ybufb, ln3g, ln3b, nullptr, (float*)d_out);
}

// Round 10
// 508.373 us; speedup vs baseline: 1.3538x; 1.1637x over previous
//
#include <hip/hip_runtime.h>
#include <stdint.h>
#include <stddef.h>

#define S_LEN 1024
#define BATCH 8
#define EMB   1024
#define NHEAD 16
#define HDIM  64
#define FDIM  4096
#define NTOK  (S_LEN*BATCH)   // 8192

typedef unsigned short u16s;
typedef __attribute__((ext_vector_type(4))) float  f32x4;
typedef __attribute__((ext_vector_type(8))) u16s   u16x8;
typedef __attribute__((ext_vector_type(4))) u16s   u16x4;
typedef __attribute__((ext_vector_type(8))) __bf16 bf16x8;

__device__ __forceinline__ u16s f2bf(float f) {
  unsigned int x = __float_as_uint(f);
  return (u16s)((x + 0x7FFFu + ((x >> 16) & 1u)) >> 16);
}
__device__ __forceinline__ float bf2f(u16s u) {
  return __uint_as_float((unsigned int)u << 16);
}

__device__ __forceinline__ f32x4 mfma_bf16(u16x8 a, u16x8 b, f32x4 c) {
  return __builtin_amdgcn_mfma_f32_16x16x32_bf16(
      __builtin_bit_cast(bf16x8, a), __builtin_bit_cast(bf16x8, b), c, 0, 0, 0);
}

__device__ __forceinline__ void gload16(const void* g, void* l) {
  __builtin_amdgcn_global_load_lds(
      (const __attribute__((address_space(1))) unsigned int*)g,
      (__attribute__((address_space(3))) unsigned int*)l, 16, 0, 0);
}

// ---------------- fused prep: all fp32->bf16 casts in ONE kernel ------------
// segments (blocks of 256 threads, 4 f32/thread):
//   [0,8192) x | [8192,9216) wq | [9216,10240) wk | [10240,11264) wv
//   [11264,12288) wo | [12288,13312) pghw | [13312,17408) fc1w | [17408,21504) fc2w
__global__ __launch_bounds__(256) void prep_kernel(
    const float* __restrict__ x, const float* __restrict__ wq,
    const float* __restrict__ wk, const float* __restrict__ wv,
    const float* __restrict__ wo, const float* __restrict__ pghw,
    const float* __restrict__ fc1w, const float* __restrict__ fc2w,
    u16s* __restrict__ xb, u16s* __restrict__ bw_qkv, u16s* __restrict__ bw_o,
    u16s* __restrict__ bw_g, u16s* __restrict__ bw_f1, u16s* __restrict__ bw_f2) {
  const int b = blockIdx.x;
  const float* src; u16s* dst; int base;
  if (b < 8192)       { src = x;    dst = xb;                base = 0; }
  else if (b < 9216)  { src = wq;   dst = bw_qkv;            base = 8192; }
  else if (b < 10240) { src = wk;   dst = bw_qkv + 1048576;  base = 9216; }
  else if (b < 11264) { src = wv;   dst = bw_qkv + 2097152;  base = 10240; }
  else if (b < 12288) { src = wo;   dst = bw_o;              base = 11264; }
  else if (b < 13312) { src = pghw; dst = bw_g;              base = 12288; }
  else if (b < 17408) { src = fc1w; dst = bw_f1;             base = 13312; }
  else                { src = fc2w; dst = bw_f2;             base = 17408; }
  const int i = (b - base) * 256 + threadIdx.x;
  float4 v = ((const float4*)src)[i];
  u16x4 o;
  o[0] = f2bf(v.x); o[1] = f2bf(v.y); o[2] = f2bf(v.z); o[3] = f2bf(v.w);
  ((u16x4*)dst)[i] = o;
}

// ---------------- fused small kernel: z projections + qkv bias concat -------
// blocks 0-3: zg = z@pgzw^T+pgzb ; 4-7: zv = z@pvw^T+pvb ; 8-19: bqkv concat
__global__ __launch_bounds__(256) void small_kernel(
    const float* __restrict__ z,
    const float* __restrict__ pgzw, const float* __restrict__ pgzb,
    const float* __restrict__ pvw,  const float* __restrict__ pvb,
    float* __restrict__ zgb, float* __restrict__ zvb,
    const float* __restrict__ bq, const float* __restrict__ bk,
    const float* __restrict__ bv, float* __restrict__ bqkv) {
  const int blk = blockIdx.x;
  if (blk < 8) {
    const int which = blk >> 2;
    const float* w    = which ? pvw : pgzw;
    const float* bias = which ? pvb : pgzb;
    float* out        = which ? zvb : zgb;
    const int o = (blk & 3) * 256 + threadIdx.x;
    float acc[8] = {};
    const float* wr = w + (size_t)o * EMB;
    for (int e = 0; e < EMB; e += 4) {
      float4 wv = *(const float4*)(wr + e);
#pragma unroll
      for (int b = 0; b < 8; ++b) {
        float4 zv = *(const float4*)(z + b * EMB + e);
        acc[b] += zv.x * wv.x + zv.y * wv.y + zv.z * wv.z + zv.w * wv.w;
      }
    }
    float bb = bias[o];
#pragma unroll
    for (int b = 0; b < 8; ++b) out[b * EMB + o] = acc[b] + bb;
  } else {
    const int i = (blk - 8) * 256 + threadIdx.x;   // 0..3071
    bqkv[i] = (i < 1024) ? bq[i] : (i < 2048) ? bk[i - 1024] : bv[i - 2048];
  }
}

// ---------------- LayerNorm (bf16 in) ----------------
// MODE 0: write bf16 ; MODE 1: write f32 (final output)
template <int MODE>
__global__ __launch_bounds__(256) void ln_kernel(const u16s* __restrict__ y,
                                                 const float* __restrict__ gam,
                                                 const float* __restrict__ bet,
                                                 u16s* __restrict__ obf,
                                                 float* __restrict__ of) {
  const int row = blockIdx.x;
  const int t = threadIdx.x;
  const u16s* yr = y + (size_t)row * EMB;
  u16x4 raw = ((const u16x4*)yr)[t];
  float4 v;
  v.x = bf2f(raw[0]); v.y = bf2f(raw[1]); v.z = bf2f(raw[2]); v.w = bf2f(raw[3]);
  float s = v.x + v.y + v.z + v.w;
  float s2 = v.x * v.x + v.y * v.y + v.z * v.z + v.w * v.w;
#pragma unroll
  for (int m = 1; m < 64; m <<= 1) { s += __shfl_xor(s, m); s2 += __shfl_xor(s2, m); }
  __shared__ float red[8];
  const int wid = t >> 6, lane = t & 63;
  if (lane == 0) { red[wid] = s; red[4 + wid] = s2; }
  __syncthreads();
  s = red[0] + red[1] + red[2] + red[3];
  s2 = red[4] + red[5] + red[6] + red[7];
  float mu = s * (1.f / EMB);
  float var = s2 * (1.f / EMB) - mu * mu;
  float rs = rsqrtf(var + 1e-5f);
  float4 g = ((const float4*)gam)[t];
  float4 b = ((const float4*)bet)[t];
  float4 o;
  o.x = (v.x - mu) * rs * g.x + b.x;
  o.y = (v.y - mu) * rs * g.y + b.y;
  o.z = (v.z - mu) * rs * g.z + b.z;
  o.w = (v.w - mu) * rs * g.w + b.w;
  if constexpr (MODE == 0) {
    u16x4 p;
    p[0] = f2bf(o.x); p[1] = f2bf(o.y); p[2] = f2bf(o.z); p[3] = f2bf(o.w);
    ((u16x4*)(obf + (size_t)row * EMB))[t] = p;
  } else {
    ((float4*)(of + (size_t)row * EMB))[t] = o;
  }
}

// ---------------- GEMM: C = A(MxK) * B(NxK)^T + bias, fused epilogues --------
// R9 core (best measured: fc1 804 TF): 128x128 tile, BK=64, 4 waves (2x2),
// 32KB LDS, 4 blocks/CU, XOR chunk swizzle (conflicts==0), swapped-operand
// epilogue (lane = 1 row x 4 cols, u16x4 stores), bn-FAST grids.
// NEW (R10): bijective XCD-CHUNK swizzle — hw block j runs orig block
// (j&7)*(nwg/8) + (j>>3), so XCD k owns orig range [k*nwg/8,(k+1)*nwg/8) =
// 8 contiguous A-row-panels x ALL bn tiles. A is fetched once globally
// (R9: fc2 re-fetched A 4.3x = 274MB because panel-siblings landed on 8
// different XCDs); weights are served L3-wide. NOTE this is the opposite
// grouping of R6's failed swizzle (bn-stripe x all bm per XCD).
enum { EPI_QKV3 = 0, EPI_RELU = 1, EPI_RES = 2, EPI_GATE = 3 };

template <int EPI>
__global__ __launch_bounds__(256, 4) void gemm_nt(const u16s* __restrict__ A,
                                                  const u16s* __restrict__ Bw,
                                                  const float* __restrict__ bias,
                                                  void* __restrict__ out,
                                                  const u16s* __restrict__ res,
                                                  const float* __restrict__ zg,
                                                  const float* __restrict__ zv,
                                                  int M, int N, int K, float scale) {
  __shared__ u16s As[128 * 64];
  __shared__ u16s Bs[128 * 64];
  const int tid = threadIdx.x;
  const int wid = tid >> 6, lane = tid & 63;
  const int wm = wid >> 1, wn = wid & 1;
  const int l15 = lane & 15, l4 = lane >> 4;

  // XCD-chunk swizzle (all grids have nwg % 8 == 0); grid is (bn-tiles, bm-tiles)
  const int nwg = gridDim.x * gridDim.y;
  int lin = blockIdx.y * gridDim.x + blockIdx.x;
  lin = (lin & 7) * (nwg >> 3) + (lin >> 3);
  const int bn0 = (lin % gridDim.x) * 128;
  const int bm0 = (lin / gridDim.x) * 128;

  const int wbase = tid & ~63;
  // per-thread staging source (linear LDS chunk ell = ii*256 + tid)
  int srowA[4], scolA[4];
#pragma unroll
  for (int ii = 0; ii < 4; ++ii) {
    const int ell = ii * 256 + tid;
    const int row = ell >> 3;
    srowA[ii] = row;
    scolA[ii] = ((ell & 7) ^ (row & 7)) * 8;
  }

  f32x4 acc[4][4] = {};
  const int nkt = K >> 6;
  for (int kt = 0; kt < nkt; ++kt) {
#pragma unroll
    for (int ii = 0; ii < 4; ++ii) {
      gload16(A + (size_t)(bm0 + srowA[ii]) * K + kt * 64 + scolA[ii],
              As + (size_t)(ii * 256 + wbase) * 8);
      gload16(Bw + (size_t)(bn0 + srowA[ii]) * K + kt * 64 + scolA[ii],
              Bs + (size_t)(ii * 256 + wbase) * 8);
    }
    __syncthreads();
#pragma unroll
    for (int kk = 0; kk < 2; ++kk) {
      const int cs = kk * 4 + l4;
      u16x8 af[4], bfr[4];
#pragma unroll
      for (int i = 0; i < 4; ++i) {
        const int row = wm * 64 + i * 16 + l15;
        af[i] = *(const u16x8*)(As + row * 64 + (cs ^ (l15 & 7)) * 8);
      }
#pragma unroll
      for (int j = 0; j < 4; ++j) {
        const int row = wn * 64 + j * 16 + l15;
        bfr[j] = *(const u16x8*)(Bs + row * 64 + (cs ^ (l15 & 7)) * 8);
      }
      __builtin_amdgcn_s_setprio(1);
#pragma unroll
      for (int i = 0; i < 4; ++i)
#pragma unroll
        for (int j = 0; j < 4; ++j)
          acc[i][j] = mfma_bf16(bfr[j], af[i], acc[i][j]);   // swapped: lane = 1 row x 4 cols
      __builtin_amdgcn_s_setprio(0);
    }
    __syncthreads();
  }

  // epilogue: lane owns M-row gr = bm0+wm*64+i*16+l15, N-cols gc0..gc0+3
  u16s* outb = (u16s*)out;
#pragma unroll
  for (int i = 0; i < 4; ++i) {
    const int gr = bm0 + wm * 64 + i * 16 + l15;
#pragma unroll
    for (int j = 0; j < 4; ++j) {
      const int gc0 = bn0 + wn * 64 + j * 16 + l4 * 4;
      const float4 bv = *(const float4*)(bias + gc0);
      float v0 = acc[i][j][0] + bv.x, v1 = acc[i][j][1] + bv.y;
      float v2 = acc[i][j][2] + bv.z, v3 = acc[i][j][3] + bv.w;
      if constexpr (EPI == EPI_QKV3) {
        const int which = gc0 >> 10, col0 = gc0 & 1023;
        const int srow = gr >> 3, b = gr & 7, h = col0 >> 6, d0 = col0 & 63;
        if (which == 0) {
          u16x4 p; p[0] = f2bf(v0 * scale); p[1] = f2bf(v1 * scale);
          p[2] = f2bf(v2 * scale); p[3] = f2bf(v3 * scale);
          *(u16x4*)(outb + (size_t)(b * 16 + h) * 65536 + srow * 64 + d0) = p;
        } else if (which == 1) {
          u16x4 p; p[0] = f2bf(v0); p[1] = f2bf(v1); p[2] = f2bf(v2); p[3] = f2bf(v3);
          *(u16x4*)(outb + 8388608 + (size_t)(b * 16 + h) * 65536 + srow * 64 + d0) = p;
        } else {
          outb[16777216 + ((size_t)(b * 16 + h) * 64 + d0 + 0) * 1024 + srow] = f2bf(v0);
          outb[16777216 + ((size_t)(b * 16 + h) * 64 + d0 + 1) * 1024 + srow] = f2bf(v1);
          outb[16777216 + ((size_t)(b * 16 + h) * 64 + d0 + 2) * 1024 + srow] = f2bf(v2);
          outb[16777216 + ((size_t)(b * 16 + h) * 64 + d0 + 3) * 1024 + srow] = f2bf(v3);
        }
      } else if constexpr (EPI == EPI_RELU) {
        u16x4 p; p[0] = f2bf(fmaxf(v0, 0.f)); p[1] = f2bf(fmaxf(v1, 0.f));
        p[2] = f2bf(fmaxf(v2, 0.f)); p[3] = f2bf(fmaxf(v3, 0.f));
        *(u16x4*)(outb + (size_t)gr * N + gc0) = p;
      } else if constexpr (EPI == EPI_RES) {
        const u16x4 rr = *(const u16x4*)(res + (size_t)gr * N + gc0);
        u16x4 p; p[0] = f2bf(v0 + bf2f(rr[0])); p[1] = f2bf(v1 + bf2f(rr[1]));
        p[2] = f2bf(v2 + bf2f(rr[2])); p[3] = f2bf(v3 + bf2f(rr[3]));
        *(u16x4*)(outb + (size_t)gr * N + gc0) = p;
      } else {  // EPI_GATE
        const float4 zg4 = *(const float4*)(zg + (gr & 7) * EMB + gc0);
        const float4 zv4 = *(const float4*)(zv + (gr & 7) * EMB + gc0);
        const u16x4 rr = *(const u16x4*)(res + (size_t)gr * EMB + gc0);
        u16x4 p;
        p[0] = f2bf(bf2f(rr[0]) + zv4.x / (1.f + __expf(-(v0 + zg4.x))));
        p[1] = f2bf(bf2f(rr[1]) + zv4.y / (1.f + __expf(-(v1 + zg4.y))));
        p[2] = f2bf(bf2f(rr[2]) + zv4.z / (1.f + __expf(-(v2 + zg4.z))));
        p[3] = f2bf(bf2f(rr[3]) + zv4.w / (1.f + __expf(-(v3 + zg4.w))));
        *(u16x4*)(outb + (size_t)gr * EMB + gc0) = p;
      }
    }
  }
}

// ---------------- causal flash attention (KVBLK=64, LDS-staged) -------------
// grid: (8 qt-pairs, 128 (b,h)); block p handles q-tiles {p, 15-p} -> 17
// K-tiles (of 64) per block (balanced). 4 waves, each owns 16 q-rows.
// K tile (64 s x 64 d) and V^T tile (64 d x 64 s) staged in LDS (stride 72),
// shared by 4 waves; next tile reg-prefetched during compute. KVBLK=64
// halves barrier rounds vs R9 (32).
__global__ __launch_bounds__(256) void attn_kernel(const u16s* __restrict__ Q,
                                                   const u16s* __restrict__ K,
                                                   const u16s* __restrict__ VT,
                                                   u16s* __restrict__ O) {
  __shared__ u16s Ks[64 * 72];
  __shared__ u16s Vs[64 * 72];
  __shared__ u16s Pl[4][16 * 72];
  const int p = blockIdx.x, bh = blockIdx.y;
  const int tid = threadIdx.x;
  const int wid = tid >> 6, lane = tid & 63;
  const int l15 = lane & 15, l4 = lane >> 4;
  const size_t hoff = (size_t)bh * (S_LEN * HDIM);
  const u16s* Qb = Q + hoff;
  const u16s* Kb = K + hoff;   // [1024 s][64 d]
  const u16s* Vb = VT + hoff;  // [64 d][1024 s]
  u16s* Pw = Pl[wid];
  const int b = bh >> 4, h = bh & 15;

  // staging geometry: chunk ell = i*256+tid -> row = ell>>3 (0..63), col (ell&7)*8
  int srow[2], scol[2];
#pragma unroll
  for (int i = 0; i < 2; ++i) {
    const int ell = i * 256 + tid;
    srow[i] = ell >> 3;
    scol[i] = (ell & 7) * 8;
  }

  for (int half = 0; half < 2; ++half) {
    const int qt = half ? (15 - p) : p;
    const int qrow = qt * 64 + wid * 16 + l15;
    const u16x8 qf0 = *(const u16x8*)(Qb + qrow * 64 + l4 * 8);
    const u16x8 qf1 = *(const u16x8*)(Qb + qrow * 64 + 32 + l4 * 8);
    f32x4 oa[4] = {};
    float mrun = -1e30f, lsum = 0.f;
    const int nkt = qt + 1;

    u16x8 kreg[2], vreg[2];
#pragma unroll
    for (int i = 0; i < 2; ++i) {
      kreg[i] = *(const u16x8*)(Kb + (size_t)srow[i] * 64 + scol[i]);
      vreg[i] = *(const u16x8*)(Vb + (size_t)srow[i] * 1024 + scol[i]);
    }

    for (int kt = 0; kt < nkt; ++kt) {
      __syncthreads();   // previous tile's LDS reads complete
#pragma unroll
      for (int i = 0; i < 2; ++i) {
        *(u16x8*)(Ks + srow[i] * 72 + scol[i]) = kreg[i];
        *(u16x8*)(Vs + srow[i] * 72 + scol[i]) = vreg[i];
      }
      __syncthreads();
      if (kt + 1 < nkt) {   // prefetch next tile
#pragma unroll
        for (int i = 0; i < 2; ++i) {
          kreg[i] = *(const u16x8*)(Kb + (size_t)((kt + 1) * 64 + srow[i]) * 64 + scol[i]);
          vreg[i] = *(const u16x8*)(Vb + (size_t)srow[i] * 1024 + (kt + 1) * 64 + scol[i]);
        }
      }
      const int kbase = kt * 64;
      f32x4 sc[4] = {};
      {
        u16x8 kfA[4], kfB[4];
#pragma unroll
        for (int g = 0; g < 4; ++g) {
          kfA[g] = *(const u16x8*)(Ks + (g * 16 + l15) * 72 + l4 * 8);
          kfB[g] = *(const u16x8*)(Ks + (g * 16 + l15) * 72 + 32 + l4 * 8);
        }
        __builtin_amdgcn_s_setprio(1);
#pragma unroll
        for (int g = 0; g < 4; ++g) {
          sc[g] = mfma_bf16(kfA[g], qf0, sc[g]);
          sc[g] = mfma_bf16(kfB[g], qf1, sc[g]);
        }
        __builtin_amdgcn_s_setprio(0);
      }
      // V fragments issued early: latency hides under softmax VALU below.
      u16x8 vf0[4], vf1[4];
#pragma unroll
      for (int df = 0; df < 4; ++df) {
        vf0[df] = *(const u16x8*)(Vs + (df * 16 + l15) * 72 + l4 * 8);
        vf1[df] = *(const u16x8*)(Vs + (df * 16 + l15) * 72 + 32 + l4 * 8);
      }

      float sv[16];
      float pmax = -1e30f;
#pragma unroll
      for (int g = 0; g < 4; ++g)
#pragma unroll
        for (int r = 0; r < 4; ++r) {
          const int kg = kbase + g * 16 + l4 * 4 + r;
          const float s0 = (kg <= qrow) ? sc[g][r] : -1e9f;
          sv[g * 4 + r] = s0;
          pmax = fmaxf(pmax, s0);
        }
      pmax = fmaxf(pmax, __shfl_xor(pmax, 16));
      pmax = fmaxf(pmax, __shfl_xor(pmax, 32));
      const float mnew = fmaxf(mrun, pmax);
      const float fsc = __expf(mrun - mnew);
      float psum = 0.f;
#pragma unroll
      for (int i = 0; i < 16; ++i) { float pv = __expf(sv[i] - mnew); sv[i] = pv; psum += pv; }
      psum += __shfl_xor(psum, 16);
      psum += __shfl_xor(psum, 32);
      lsum = lsum * fsc + psum;
      mrun = mnew;
#pragma unroll
      for (int df = 0; df < 4; ++df) oa[df] *= fsc;

#pragma unroll
      for (int g = 0; g < 4; ++g) {
        u16x4 pk;
#pragma unroll
        for (int r = 0; r < 4; ++r) pk[r] = f2bf(sv[g * 4 + r]);
        *(u16x4*)(Pw + l15 * 72 + g * 16 + l4 * 4) = pk;
      }
      asm volatile("s_waitcnt lgkmcnt(0)" ::: "memory");
      const u16x8 pf0 = *(const u16x8*)(Pw + l15 * 72 + l4 * 8);
      const u16x8 pf1 = *(const u16x8*)(Pw + l15 * 72 + 32 + l4 * 8);
      __builtin_amdgcn_s_setprio(1);
#pragma unroll
      for (int df = 0; df < 4; ++df) {
        oa[df] = mfma_bf16(vf0[df], pf0, oa[df]);
        oa[df] = mfma_bf16(vf1[df], pf1, oa[df]);
      }
      __builtin_amdgcn_s_setprio(0);
    }
    const float inv = 1.f / lsum;
    u16s* orow = O + ((size_t)qrow * 8 + b) * EMB + h * 64;
#pragma unroll
    for (int df = 0; df < 4; ++df)
#pragma unroll
      for (int r = 0; r < 4; ++r)
        orow[df * 16 + l4 * 4 + r] = f2bf(oa[df][r] * inv);
  }
}

// ---------------- driver ----------------
extern "C" void kernel_launch(void* const* d_in, const int* in_sizes, int n_in,
                              void* d_out, int out_size, void* d_ws, size_t ws_size,
                              hipStream_t stream) {
  const float* x = (const float*)d_in[0];
  const float* z = (const float*)d_in[1];
  const float* wq = (const float*)d_in[2];  const float* bq = (const float*)d_in[3];
  const float* wk = (const float*)d_in[4];  const float* bk = (const float*)d_in[5];
  const float* wv = (const float*)d_in[6];  const float* bv = (const float*)d_in[7];
  const float* wo = (const float*)d_in[8];  const float* bo = (const float*)d_in[9];
  const float* ln1g = (const float*)d_in[10]; const float* ln1b = (const float*)d_in[11];
  const float* pghw = (const float*)d_in[12]; const float* pghb = (const float*)d_in[13];
  const float* pgzw = (const float*)d_in[14]; const float* pgzb = (const float*)d_in[15];
  const float* pvw  = (const float*)d_in[16]; const float* pvb  = (const float*)d_in[17];
  const float* ln2g = (const float*)d_in[18]; const float* ln2b = (const float*)d_in[19];
  const float* fc1w = (const float*)d_in[20]; const float* fc1b = (const float*)d_in[21];
  const float* fc2w = (const float*)d_in[22]; const float* fc2b = (const float*)d_in[23];
  const float* ln3g = (const float*)d_in[24]; const float* ln3b = (const float*)d_in[25];

  char* ws = (char*)d_ws;
  size_t off = 0;
  auto alloc = [&](size_t bytes) -> char* {
    char* p = ws + off;
    off += (bytes + 255) & ~(size_t)255;
    return p;
  };

  u16s* bw_qkv = (u16s*)alloc(2u * 3145728);  // wq|wk|wv concat (3072x1024)
  u16s* bw_o = (u16s*)alloc(2u * 1048576);
  u16s* bw_g = (u16s*)alloc(2u * 1048576);
  u16s* bw_f1 = (u16s*)alloc(2u * 4194304);
  u16s* bw_f2 = (u16s*)alloc(2u * 4194304);
  u16s* xb = (u16s*)alloc(2u * 8388608);
  // qh, kh, vT, attnb are four contiguous 16MB buffers (the QKV3 epilogue
  // relies on qh+8388608 == kh, qh+16777216 == vT); hbuf (8192x4096 bf16 =
  // 64MB) aliases all four. vT is V pre-transposed per head: vT[bh][64][1024].
  u16s* qh = (u16s*)alloc(2u * 8388608);
  u16s* kh = (u16s*)alloc(2u * 8388608);
  u16s* vT = (u16s*)alloc(2u * 8388608);
  u16s* attnb = (u16s*)alloc(2u * 8388608);
  u16s* hbuf = qh;
  u16s* ybufb = (u16s*)alloc(2u * 8388608);   // bf16 pre-LN buffer
  u16s* x1b = (u16s*)alloc(2u * 8388608);     // LN1 output (bf16)
  u16s* x2b = (u16s*)alloc(2u * 8388608);     // LN2 output (bf16)
  float* zgb = (float*)alloc(4u * 8192);
  float* zvb = (float*)alloc(4u * 8192);
  float* bqkv = (float*)alloc(4u * 3072);
  (void)off; (void)ws_size; (void)in_sizes; (void)n_in; (void)out_size;
  (void)kh; (void)vT;

  // fused prep: all casts in one launch; z-projections + bias concat in one
  prep_kernel<<<21504, 256, 0, stream>>>(x, wq, wk, wv, wo, pghw, fc1w, fc2w,
                                         xb, bw_qkv, bw_o, bw_g, bw_f1, bw_f2);
  small_kernel<<<20, 256, 0, stream>>>(z, pgzw, pgzb, pvw, pvb, zgb, zvb,
                                       bq, bk, bv, bqkv);

  // fused QKV projection (N=3072) with head-scatter epilogue; grids are
  // (N-tiles, M-tiles): bn is the fast axis; XCD-chunk swizzle inside.
  gemm_nt<EPI_QKV3><<<dim3(24, 64), 256, 0, stream>>>(
      xb, bw_qkv, bqkv, qh, nullptr, nullptr, nullptr, NTOK, 3072, EMB, 0.125f);

  attn_kernel<<<dim3(8, 128), 256, 0, stream>>>(qh, kh, vT, attnb);

  // out-proj + residual(xb) -> ybufb (bf16), then LN1 -> x1b
  gemm_nt<EPI_RES><<<dim3(8, 64), 256, 0, stream>>>(
      attnb, bw_o, bo, ybufb, xb, nullptr, nullptr, NTOK, EMB, EMB, 1.f);
  ln_kernel<0><<<NTOK, 256, 0, stream>>>(ybufb, ln1g, ln1b, x1b, nullptr);

  // gated fusion (residual x1b) -> ybufb, then LN2 -> x2b
  gemm_nt<EPI_GATE><<<dim3(8, 64), 256, 0, stream>>>(
      x1b, bw_g, pghb, ybufb, x1b, zgb, zvb, NTOK, EMB, EMB, 1.f);
  ln_kernel<0><<<NTOK, 256, 0, stream>>>(ybufb, ln2g, ln2b, x2b, nullptr);

  // FFN (residual x2b) -> ybufb, then LN3 -> d_out (f32)
  gemm_nt<EPI_RELU><<<dim3(32, 64), 256, 0, stream>>>(
      x2b, bw_f1, fc1b, hbuf, nullptr, nullptr, nullptr, NTOK, FDIM, EMB, 1.f);
  gemm_nt<EPI_RES><<<dim3(8, 64), 256, 0, stream>>>(
      hbuf, bw_f2, fc2b, ybufb, x2b, nullptr, nullptr, NTOK, EMB, FDIM, 1.f);
  ln_kernel<1><<<NTOK, 256, 0, stream>>>(ybufb, ln3g, ln3b, nullptr, (float*)d_out);
}

// Round 11
// 437.713 us; speedup vs baseline: 1.5723x; 1.1614x over previous
//
#include <hip/hip_runtime.h>
#include <stdint.h>
#include <stddef.h>

#define S_LEN 1024
#define BATCH 8
#define EMB   1024
#define NHEAD 16
#define HDIM  64
#define FDIM  4096
#define NTOK  (S_LEN*BATCH)   // 8192

typedef unsigned short u16s;
typedef __attribute__((ext_vector_type(4))) float  f32x4;
typedef __attribute__((ext_vector_type(8))) u16s   u16x8;
typedef __attribute__((ext_vector_type(4))) u16s   u16x4;
typedef __attribute__((ext_vector_type(8))) __bf16 bf16x8;

__device__ __forceinline__ u16s f2bf(float f) {
  unsigned int x = __float_as_uint(f);
  return (u16s)((x + 0x7FFFu + ((x >> 16) & 1u)) >> 16);
}
__device__ __forceinline__ float bf2f(u16s u) {
  return __uint_as_float((unsigned int)u << 16);
}

__device__ __forceinline__ f32x4 mfma_bf16(u16x8 a, u16x8 b, f32x4 c) {
  return __builtin_amdgcn_mfma_f32_16x16x32_bf16(
      __builtin_bit_cast(bf16x8, a), __builtin_bit_cast(bf16x8, b), c, 0, 0, 0);
}

__device__ __forceinline__ void gload16(const void* g, void* l) {
  __builtin_amdgcn_global_load_lds(
      (const __attribute__((address_space(1))) unsigned int*)g,
      (__attribute__((address_space(3))) unsigned int*)l, 16, 0, 0);
}

// ---------------- fused prep: all fp32->bf16 casts in ONE kernel ------------
// segments (blocks of 256 threads, 4 f32/thread):
//   [0,8192) x | [8192,9216) wq | [9216,10240) wk | [10240,11264) wv
//   [11264,12288) wo | [12288,13312) pghw | [13312,17408) fc1w | [17408,21504) fc2w
__global__ __launch_bounds__(256) void prep_kernel(
    const float* __restrict__ x, const float* __restrict__ wq,
    const float* __restrict__ wk, const float* __restrict__ wv,
    const float* __restrict__ wo, const float* __restrict__ pghw,
    const float* __restrict__ fc1w, const float* __restrict__ fc2w,
    u16s* __restrict__ xb, u16s* __restrict__ bw_qkv, u16s* __restrict__ bw_o,
    u16s* __restrict__ bw_g, u16s* __restrict__ bw_f1, u16s* __restrict__ bw_f2) {
  const int b = blockIdx.x;
  const float* src; u16s* dst; int base;
  if (b < 8192)       { src = x;    dst = xb;                base = 0; }
  else if (b < 9216)  { src = wq;   dst = bw_qkv;            base = 8192; }
  else if (b < 10240) { src = wk;   dst = bw_qkv + 1048576;  base = 9216; }
  else if (b < 11264) { src = wv;   dst = bw_qkv + 2097152;  base = 10240; }
  else if (b < 12288) { src = wo;   dst = bw_o;              base = 11264; }
  else if (b < 13312) { src = pghw; dst = bw_g;              base = 12288; }
  else if (b < 17408) { src = fc1w; dst = bw_f1;             base = 13312; }
  else                { src = fc2w; dst = bw_f2;             base = 17408; }
  const int i = (b - base) * 256 + threadIdx.x;
  float4 v = ((const float4*)src)[i];
  u16x4 o;
  o[0] = f2bf(v.x); o[1] = f2bf(v.y); o[2] = f2bf(v.z); o[3] = f2bf(v.w);
  ((u16x4*)dst)[i] = o;
}

// ---------------- fused small kernel: z projections + qkv bias concat -------
// WAVE-PARALLEL zproj (R10's 20-block version ran 85us at 0.4% VALUBusy --
// 8 blocks walked a 256-iter serial K-loop while 97% of the GPU idled).
// blocks 0..511: one wave per output element. wave handles out idx
// = blk*4+wid (0..2047); which = idx>>10 selects {pgzw,pgh? no: pgzw,pvw};
// lane l covers K elems [l*16,l*16+16): 4 float4 of w + 8x4 float4 of z
// (z = 32KB, L2/L1-hot), butterfly shfl reduce, lanes 0-7 write batch b=lane.
// blocks 512..523: qkv bias concat (12x256 = 3072).
__global__ __launch_bounds__(256) void small_kernel(
    const float* __restrict__ z,
    const float* __restrict__ pgzw, const float* __restrict__ pgzb,
    const float* __restrict__ pvw,  const float* __restrict__ pvb,
    float* __restrict__ zgb, float* __restrict__ zvb,
    const float* __restrict__ bq, const float* __restrict__ bk,
    const float* __restrict__ bv, float* __restrict__ bqkv) {
  const int blk = blockIdx.x;
  if (blk < 512) {
    const int wid = threadIdx.x >> 6, lane = threadIdx.x & 63;
    const int idx = blk * 4 + wid;           // 0..2047
    const int which = idx >> 10, o = idx & 1023;
    const float* w    = which ? pvw : pgzw;
    const float* bias = which ? pvb : pgzb;
    float* out        = which ? zvb : zgb;
    const float* wr = w + (size_t)o * EMB + lane * 16;
    float wv[16];
#pragma unroll
    for (int c = 0; c < 4; ++c) {
      float4 t = *(const float4*)(wr + c * 4);
      wv[c * 4 + 0] = t.x; wv[c * 4 + 1] = t.y; wv[c * 4 + 2] = t.z; wv[c * 4 + 3] = t.w;
    }
    float acc[8];
#pragma unroll
    for (int b = 0; b < 8; ++b) {
      const float* zr = z + b * EMB + lane * 16;
      float s = 0.f;
#pragma unroll
      for (int c = 0; c < 4; ++c) {
        float4 t = *(const float4*)(zr + c * 4);
        s += t.x * wv[c * 4 + 0] + t.y * wv[c * 4 + 1] +
             t.z * wv[c * 4 + 2] + t.w * wv[c * 4 + 3];
      }
      acc[b] = s;
    }
#pragma unroll
    for (int m = 1; m < 64; m <<= 1)
#pragma unroll
      for (int b = 0; b < 8; ++b) acc[b] += __shfl_xor(acc[b], m);
    if (lane < 8) out[lane * EMB + o] = acc[lane] + bias[o];
  } else {
    const int i = (blk - 512) * 256 + threadIdx.x;   // 0..3071
    bqkv[i] = (i < 1024) ? bq[i] : (i < 2048) ? bk[i - 1024] : bv[i - 2048];
  }
}

// ---------------- LayerNorm (bf16 in) ----------------
// MODE 0: write bf16 ; MODE 1: write f32 (final output)
template <int MODE>
__global__ __launch_bounds__(256) void ln_kernel(const u16s* __restrict__ y,
                                                 const float* __restrict__ gam,
                                                 const float* __restrict__ bet,
                                                 u16s* __restrict__ obf,
                                                 float* __restrict__ of) {
  const int row = blockIdx.x;
  const int t = threadIdx.x;
  const u16s* yr = y + (size_t)row * EMB;
  u16x4 raw = ((const u16x4*)yr)[t];
  float4 v;
  v.x = bf2f(raw[0]); v.y = bf2f(raw[1]); v.z = bf2f(raw[2]); v.w = bf2f(raw[3]);
  float s = v.x + v.y + v.z + v.w;
  float s2 = v.x * v.x + v.y * v.y + v.z * v.z + v.w * v.w;
#pragma unroll
  for (int m = 1; m < 64; m <<= 1) { s += __shfl_xor(s, m); s2 += __shfl_xor(s2, m); }
  __shared__ float red[8];
  const int wid = t >> 6, lane = t & 63;
  if (lane == 0) { red[wid] = s; red[4 + wid] = s2; }
  __syncthreads();
  s = red[0] + red[1] + red[2] + red[3];
  s2 = red[4] + red[5] + red[6] + red[7];
  float mu = s * (1.f / EMB);
  float var = s2 * (1.f / EMB) - mu * mu;
  float rs = rsqrtf(var + 1e-5f);
  float4 g = ((const float4*)gam)[t];
  float4 b = ((const float4*)bet)[t];
  float4 o;
  o.x = (v.x - mu) * rs * g.x + b.x;
  o.y = (v.y - mu) * rs * g.y + b.y;
  o.z = (v.z - mu) * rs * g.z + b.z;
  o.w = (v.w - mu) * rs * g.w + b.w;
  if constexpr (MODE == 0) {
    u16x4 p;
    p[0] = f2bf(o.x); p[1] = f2bf(o.y); p[2] = f2bf(o.z); p[3] = f2bf(o.w);
    ((u16x4*)(obf + (size_t)row * EMB))[t] = p;
  } else {
    ((float4*)(of + (size_t)row * EMB))[t] = o;
  }
}

// ---------------- GEMM: C = A(MxK) * B(NxK)^T + bias, fused epilogues --------
// R9 core (best measured: fc1 808 TF): 128x128 tile, BK=64, 4 waves (2x2),
// 32KB LDS, 4 blocks/CU, XOR chunk swizzle (conflicts==0), swapped-operand
// epilogue (lane = 1 row x 4 cols, u16x4 stores), bn-FAST grids, bijective
// XCD-CHUNK swizzle (XCD k owns 8 contiguous A-row-panels x all bn tiles).
enum { EPI_QKV3 = 0, EPI_RELU = 1, EPI_RES = 2, EPI_GATE = 3 };

template <int EPI>
__global__ __launch_bounds__(256, 4) void gemm_nt(const u16s* __restrict__ A,
                                                  const u16s* __restrict__ Bw,
                                                  const float* __restrict__ bias,
                                                  void* __restrict__ out,
                                                  const u16s* __restrict__ res,
                                                  const float* __restrict__ zg,
                                                  const float* __restrict__ zv,
                                                  int M, int N, int K, float scale) {
  __shared__ u16s As[128 * 64];
  __shared__ u16s Bs[128 * 64];
  const int tid = threadIdx.x;
  const int wid = tid >> 6, lane = tid & 63;
  const int wm = wid >> 1, wn = wid & 1;
  const int l15 = lane & 15, l4 = lane >> 4;

  // XCD-chunk swizzle (all grids have nwg % 8 == 0); grid is (bn-tiles, bm-tiles)
  const int nwg = gridDim.x * gridDim.y;
  int lin = blockIdx.y * gridDim.x + blockIdx.x;
  lin = (lin & 7) * (nwg >> 3) + (lin >> 3);
  const int bn0 = (lin % gridDim.x) * 128;
  const int bm0 = (lin / gridDim.x) * 128;

  const int wbase = tid & ~63;
  // per-thread staging source (linear LDS chunk ell = ii*256 + tid)
  int srowA[4], scolA[4];
#pragma unroll
  for (int ii = 0; ii < 4; ++ii) {
    const int ell = ii * 256 + tid;
    const int row = ell >> 3;
    srowA[ii] = row;
    scolA[ii] = ((ell & 7) ^ (row & 7)) * 8;
  }

  f32x4 acc[4][4] = {};
  const int nkt = K >> 6;
  for (int kt = 0; kt < nkt; ++kt) {
#pragma unroll
    for (int ii = 0; ii < 4; ++ii) {
      gload16(A + (size_t)(bm0 + srowA[ii]) * K + kt * 64 + scolA[ii],
              As + (size_t)(ii * 256 + wbase) * 8);
      gload16(Bw + (size_t)(bn0 + srowA[ii]) * K + kt * 64 + scolA[ii],
              Bs + (size_t)(ii * 256 + wbase) * 8);
    }
    __syncthreads();
#pragma unroll
    for (int kk = 0; kk < 2; ++kk) {
      const int cs = kk * 4 + l4;
      u16x8 af[4], bfr[4];
#pragma unroll
      for (int i = 0; i < 4; ++i) {
        const int row = wm * 64 + i * 16 + l15;
        af[i] = *(const u16x8*)(As + row * 64 + (cs ^ (l15 & 7)) * 8);
      }
#pragma unroll
      for (int j = 0; j < 4; ++j) {
        const int row = wn * 64 + j * 16 + l15;
        bfr[j] = *(const u16x8*)(Bs + row * 64 + (cs ^ (l15 & 7)) * 8);
      }
      __builtin_amdgcn_s_setprio(1);
#pragma unroll
      for (int i = 0; i < 4; ++i)
#pragma unroll
        for (int j = 0; j < 4; ++j)
          acc[i][j] = mfma_bf16(bfr[j], af[i], acc[i][j]);   // swapped: lane = 1 row x 4 cols
      __builtin_amdgcn_s_setprio(0);
    }
    __syncthreads();
  }

  // epilogue: lane owns M-row gr = bm0+wm*64+i*16+l15, N-cols gc0..gc0+3
  u16s* outb = (u16s*)out;
#pragma unroll
  for (int i = 0; i < 4; ++i) {
    const int gr = bm0 + wm * 64 + i * 16 + l15;
#pragma unroll
    for (int j = 0; j < 4; ++j) {
      const int gc0 = bn0 + wn * 64 + j * 16 + l4 * 4;
      const float4 bv = *(const float4*)(bias + gc0);
      float v0 = acc[i][j][0] + bv.x, v1 = acc[i][j][1] + bv.y;
      float v2 = acc[i][j][2] + bv.z, v3 = acc[i][j][3] + bv.w;
      if constexpr (EPI == EPI_QKV3) {
        const int which = gc0 >> 10, col0 = gc0 & 1023;
        const int srow = gr >> 3, b = gr & 7, h = col0 >> 6, d0 = col0 & 63;
        if (which == 0) {
          u16x4 p; p[0] = f2bf(v0 * scale); p[1] = f2bf(v1 * scale);
          p[2] = f2bf(v2 * scale); p[3] = f2bf(v3 * scale);
          *(u16x4*)(outb + (size_t)(b * 16 + h) * 65536 + srow * 64 + d0) = p;
        } else if (which == 1) {
          u16x4 p; p[0] = f2bf(v0); p[1] = f2bf(v1); p[2] = f2bf(v2); p[3] = f2bf(v3);
          *(u16x4*)(outb + 8388608 + (size_t)(b * 16 + h) * 65536 + srow * 64 + d0) = p;
        } else {
          outb[16777216 + ((size_t)(b * 16 + h) * 64 + d0 + 0) * 1024 + srow] = f2bf(v0);
          outb[16777216 + ((size_t)(b * 16 + h) * 64 + d0 + 1) * 1024 + srow] = f2bf(v1);
          outb[16777216 + ((size_t)(b * 16 + h) * 64 + d0 + 2) * 1024 + srow] = f2bf(v2);
          outb[16777216 + ((size_t)(b * 16 + h) * 64 + d0 + 3) * 1024 + srow] = f2bf(v3);
        }
      } else if constexpr (EPI == EPI_RELU) {
        u16x4 p; p[0] = f2bf(fmaxf(v0, 0.f)); p[1] = f2bf(fmaxf(v1, 0.f));
        p[2] = f2bf(fmaxf(v2, 0.f)); p[3] = f2bf(fmaxf(v3, 0.f));
        *(u16x4*)(outb + (size_t)gr * N + gc0) = p;
      } else if constexpr (EPI == EPI_RES) {
        const u16x4 rr = *(const u16x4*)(res + (size_t)gr * N + gc0);
        u16x4 p; p[0] = f2bf(v0 + bf2f(rr[0])); p[1] = f2bf(v1 + bf2f(rr[1]));
        p[2] = f2bf(v2 + bf2f(rr[2])); p[3] = f2bf(v3 + bf2f(rr[3]));
        *(u16x4*)(outb + (size_t)gr * N + gc0) = p;
      } else {  // EPI_GATE
        const float4 zg4 = *(const float4*)(zg + (gr & 7) * EMB + gc0);
        const float4 zv4 = *(const float4*)(zv + (gr & 7) * EMB + gc0);
        const u16x4 rr = *(const u16x4*)(res + (size_t)gr * EMB + gc0);
        u16x4 p;
        p[0] = f2bf(bf2f(rr[0]) + zv4.x / (1.f + __expf(-(v0 + zg4.x))));
        p[1] = f2bf(bf2f(rr[1]) + zv4.y / (1.f + __expf(-(v1 + zg4.y))));
        p[2] = f2bf(bf2f(rr[2]) + zv4.z / (1.f + __expf(-(v2 + zg4.z))));
        p[3] = f2bf(bf2f(rr[3]) + zv4.w / (1.f + __expf(-(v3 + zg4.w))));
        *(u16x4*)(outb + (size_t)gr * EMB + gc0) = p;
      }
    }
  }
}

// ---------------- causal flash attention (KVBLK=64, LDS-staged) -------------
// grid: (8 qt-pairs, 128 (b,h)); block p handles q-tiles {p, 15-p} -> 17
// K-tiles (of 64) per block (balanced). 4 waves, each owns 16 q-rows.
// K tile (64 s x 64 d) and V^T tile (64 d x 64 s) staged in LDS (stride 72),
// shared by 4 waves; next tile reg-prefetched during compute.
__global__ __launch_bounds__(256) void attn_kernel(const u16s* __restrict__ Q,
                                                   const u16s* __restrict__ K,
                                                   const u16s* __restrict__ VT,
                                                   u16s* __restrict__ O) {
  __shared__ u16s Ks[64 * 72];
  __shared__ u16s Vs[64 * 72];
  __shared__ u16s Pl[4][16 * 72];
  const int p = blockIdx.x, bh = blockIdx.y;
  const int tid = threadIdx.x;
  const int wid = tid >> 6, lane = tid & 63;
  const int l15 = lane & 15, l4 = lane >> 4;
  const size_t hoff = (size_t)bh * (S_LEN * HDIM);
  const u16s* Qb = Q + hoff;
  const u16s* Kb = K + hoff;   // [1024 s][64 d]
  const u16s* Vb = VT + hoff;  // [64 d][1024 s]
  u16s* Pw = Pl[wid];
  const int b = bh >> 4, h = bh & 15;

  // staging geometry: chunk ell = i*256+tid -> row = ell>>3 (0..63), col (ell&7)*8
  int srow[2], scol[2];
#pragma unroll
  for (int i = 0; i < 2; ++i) {
    const int ell = i * 256 + tid;
    srow[i] = ell >> 3;
    scol[i] = (ell & 7) * 8;
  }

  for (int half = 0; half < 2; ++half) {
    const int qt = half ? (15 - p) : p;
    const int qrow = qt * 64 + wid * 16 + l15;
    const u16x8 qf0 = *(const u16x8*)(Qb + qrow * 64 + l4 * 8);
    const u16x8 qf1 = *(const u16x8*)(Qb + qrow * 64 + 32 + l4 * 8);
    f32x4 oa[4] = {};
    float mrun = -1e30f, lsum = 0.f;
    const int nkt = qt + 1;

    u16x8 kreg[2], vreg[2];
#pragma unroll
    for (int i = 0; i < 2; ++i) {
      kreg[i] = *(const u16x8*)(Kb + (size_t)srow[i] * 64 + scol[i]);
      vreg[i] = *(const u16x8*)(Vb + (size_t)srow[i] * 1024 + scol[i]);
    }

    for (int kt = 0; kt < nkt; ++kt) {
      __syncthreads();   // previous tile's LDS reads complete
#pragma unroll
      for (int i = 0; i < 2; ++i) {
        *(u16x8*)(Ks + srow[i] * 72 + scol[i]) = kreg[i];
        *(u16x8*)(Vs + srow[i] * 72 + scol[i]) = vreg[i];
      }
      __syncthreads();
      if (kt + 1 < nkt) {   // prefetch next tile
#pragma unroll
        for (int i = 0; i < 2; ++i) {
          kreg[i] = *(const u16x8*)(Kb + (size_t)((kt + 1) * 64 + srow[i]) * 64 + scol[i]);
          vreg[i] = *(const u16x8*)(Vb + (size_t)srow[i] * 1024 + (kt + 1) * 64 + scol[i]);
        }
      }
      const int kbase = kt * 64;
      f32x4 sc[4] = {};
      {
        u16x8 kfA[4], kfB[4];
#pragma unroll
        for (int g = 0; g < 4; ++g) {
          kfA[g] = *(const u16x8*)(Ks + (g * 16 + l15) * 72 + l4 * 8);
          kfB[g] = *(const u16x8*)(Ks + (g * 16 + l15) * 72 + 32 + l4 * 8);
        }
        __builtin_amdgcn_s_setprio(1);
#pragma unroll
        for (int g = 0; g < 4; ++g) {
          sc[g] = mfma_bf16(kfA[g], qf0, sc[g]);
          sc[g] = mfma_bf16(kfB[g], qf1, sc[g]);
        }
        __builtin_amdgcn_s_setprio(0);
      }
      // V fragments issued early: latency hides under softmax VALU below.
      u16x8 vf0[4], vf1[4];
#pragma unroll
      for (int df = 0; df < 4; ++df) {
        vf0[df] = *(const u16x8*)(Vs + (df * 16 + l15) * 72 + l4 * 8);
        vf1[df] = *(const u16x8*)(Vs + (df * 16 + l15) * 72 + 32 + l4 * 8);
      }

      float sv[16];
      float pmax = -1e30f;
#pragma unroll
      for (int g = 0; g < 4; ++g)
#pragma unroll
        for (int r = 0; r < 4; ++r) {
          const int kg = kbase + g * 16 + l4 * 4 + r;
          const float s0 = (kg <= qrow) ? sc[g][r] : -1e9f;
          sv[g * 4 + r] = s0;
          pmax = fmaxf(pmax, s0);
        }
      pmax = fmaxf(pmax, __shfl_xor(pmax, 16));
      pmax = fmaxf(pmax, __shfl_xor(pmax, 32));
      const float mnew = fmaxf(mrun, pmax);
      const float fsc = __expf(mrun - mnew);
      float psum = 0.f;
#pragma unroll
      for (int i = 0; i < 16; ++i) { float pv = __expf(sv[i] - mnew); sv[i] = pv; psum += pv; }
      psum += __shfl_xor(psum, 16);
      psum += __shfl_xor(psum, 32);
      lsum = lsum * fsc + psum;
      mrun = mnew;
#pragma unroll
      for (int df = 0; df < 4; ++df) oa[df] *= fsc;

#pragma unroll
      for (int g = 0; g < 4; ++g) {
        u16x4 pk;
#pragma unroll
        for (int r = 0; r < 4; ++r) pk[r] = f2bf(sv[g * 4 + r]);
        *(u16x4*)(Pw + l15 * 72 + g * 16 + l4 * 4) = pk;
      }
      asm volatile("s_waitcnt lgkmcnt(0)" ::: "memory");
      const u16x8 pf0 = *(const u16x8*)(Pw + l15 * 72 + l4 * 8);
      const u16x8 pf1 = *(const u16x8*)(Pw + l15 * 72 + 32 + l4 * 8);
      __builtin_amdgcn_s_setprio(1);
#pragma unroll
      for (int df = 0; df < 4; ++df) {
        oa[df] = mfma_bf16(vf0[df], pf0, oa[df]);
        oa[df] = mfma_bf16(vf1[df], pf1, oa[df]);
      }
      __builtin_amdgcn_s_setprio(0);
    }
    const float inv = 1.f / lsum;
    u16s* orow = O + ((size_t)qrow * 8 + b) * EMB + h * 64;
#pragma unroll
    for (int df = 0; df < 4; ++df)
#pragma unroll
      for (int r = 0; r < 4; ++r)
        orow[df * 16 + l4 * 4 + r] = f2bf(oa[df][r] * inv);
  }
}

// ---------------- driver ----------------
extern "C" void kernel_launch(void* const* d_in, const int* in_sizes, int n_in,
                              void* d_out, int out_size, void* d_ws, size_t ws_size,
                              hipStream_t stream) {
  const float* x = (const float*)d_in[0];
  const float* z = (const float*)d_in[1];
  const float* wq = (const float*)d_in[2];  const float* bq = (const float*)d_in[3];
  const float* wk = (const float*)d_in[4];  const float* bk = (const float*)d_in[5];
  const float* wv = (const float*)d_in[6];  const float* bv = (const float*)d_in[7];
  const float* wo = (const float*)d_in[8];  const float* bo = (const float*)d_in[9];
  const float* ln1g = (const float*)d_in[10]; const float* ln1b = (const float*)d_in[11];
  const float* pghw = (const float*)d_in[12]; const float* pghb = (const float*)d_in[13];
  const float* pgzw = (const float*)d_in[14]; const float* pgzb = (const float*)d_in[15];
  const float* pvw  = (const float*)d_in[16]; const float* pvb  = (const float*)d_in[17];
  const float* ln2g = (const float*)d_in[18]; const float* ln2b = (const float*)d_in[19];
  const float* fc1w = (const float*)d_in[20]; const float* fc1b = (const float*)d_in[21];
  const float* fc2w = (const float*)d_in[22]; const float* fc2b = (const float*)d_in[23];
  const float* ln3g = (const float*)d_in[24]; const float* ln3b = (const float*)d_in[25];

  char* ws = (char*)d_ws;
  size_t off = 0;
  auto alloc = [&](size_t bytes) -> char* {
    char* p = ws + off;
    off += (bytes + 255) & ~(size_t)255;
    return p;
  };

  u16s* bw_qkv = (u16s*)alloc(2u * 3145728);  // wq|wk|wv concat (3072x1024)
  u16s* bw_o = (u16s*)alloc(2u * 1048576);
  u16s* bw_g = (u16s*)alloc(2u * 1048576);
  u16s* bw_f1 = (u16s*)alloc(2u * 4194304);
  u16s* bw_f2 = (u16s*)alloc(2u * 4194304);
  u16s* xb = (u16s*)alloc(2u * 8388608);
  // qh, kh, vT, attnb are four contiguous 16MB buffers (the QKV3 epilogue
  // relies on qh+8388608 == kh, qh+16777216 == vT); hbuf (8192x4096 bf16 =
  // 64MB) aliases all four. vT is V pre-transposed per head: vT[bh][64][1024].
  u16s* qh = (u16s*)alloc(2u * 8388608);
  u16s* kh = (u16s*)alloc(2u * 8388608);
  u16s* vT = (u16s*)alloc(2u * 8388608);
  u16s* attnb = (u16s*)alloc(2u * 8388608);
  u16s* hbuf = qh;
  u16s* ybufb = (u16s*)alloc(2u * 8388608);   // bf16 pre-LN buffer
  u16s* x1b = (u16s*)alloc(2u * 8388608);     // LN1 output (bf16)
  u16s* x2b = (u16s*)alloc(2u * 8388608);     // LN2 output (bf16)
  float* zgb = (float*)alloc(4u * 8192);
  float* zvb = (float*)alloc(4u * 8192);
  float* bqkv = (float*)alloc(4u * 3072);
  (void)off; (void)ws_size; (void)in_sizes; (void)n_in; (void)out_size;
  (void)kh; (void)vT;

  // fused prep: all casts in one launch; z-projections + bias concat in one
  prep_kernel<<<21504, 256, 0, stream>>>(x, wq, wk, wv, wo, pghw, fc1w, fc2w,
                                         xb, bw_qkv, bw_o, bw_g, bw_f1, bw_f2);
  small_kernel<<<524, 256, 0, stream>>>(z, pgzw, pgzb, pvw, pvb, zgb, zvb,
                                        bq, bk, bv, bqkv);

  // fused QKV projection (N=3072) with head-scatter epilogue; grids are
  // (N-tiles, M-tiles): bn is the fast axis; XCD-chunk swizzle inside.
  gemm_nt<EPI_QKV3><<<dim3(24, 64), 256, 0, stream>>>(
      xb, bw_qkv, bqkv, qh, nullptr, nullptr, nullptr, NTOK, 3072, EMB, 0.125f);

  attn_kernel<<<dim3(8, 128), 256, 0, stream>>>(qh, kh, vT, attnb);

  // out-proj + residual(xb) -> ybufb (bf16), then LN1 -> x1b
  gemm_nt<EPI_RES><<<dim3(8, 64), 256, 0, stream>>>(
      attnb, bw_o, bo, ybufb, xb, nullptr, nullptr, NTOK, EMB, EMB, 1.f);
  ln_kernel<0><<<NTOK, 256, 0, stream>>>(ybufb, ln1g, ln1b, x1b, nullptr);

  // gated fusion (residual x1b) -> ybufb, then LN2 -> x2b
  gemm_nt<EPI_GATE><<<dim3(8, 64), 256, 0, stream>>>(
      x1b, bw_g, pghb, ybufb, x1b, zgb, zvb, NTOK, EMB, EMB, 1.f);
  ln_kernel<0><<<NTOK, 256, 0, stream>>>(ybufb, ln2g, ln2b, x2b, nullptr);

  // FFN (residual x2b) -> ybufb, then LN3 -> d_out (f32)
  gemm_nt<EPI_RELU><<<dim3(32, 64), 256, 0, stream>>>(
      x2b, bw_f1, fc1b, hbuf, nullptr, nullptr, nullptr, NTOK, FDIM, EMB, 1.f);
  gemm_nt<EPI_RES><<<dim3(8, 64), 256, 0, stream>>>(
      hbuf, bw_f2, fc2b, ybufb, x2b, nullptr, nullptr, NTOK, EMB, FDIM, 1.f);
  ln_kernel<1><<<NTOK, 256, 0, stream>>>(ybufb, ln3g, ln3b, nullptr, (float*)d_out);
}